// Round 1
// 714.571 us; speedup vs baseline: 1.1524x; 1.1524x over previous
//
#include <hip/hip_runtime.h>
#include <math.h>

// Problem constants
#define BS_ 4
#define N_  2048
#define D_  1024
#define H_  8
#define DH_ 128

typedef __attribute__((ext_vector_type(8))) short short8;
typedef __attribute__((ext_vector_type(4))) short short4_t;
typedef __attribute__((ext_vector_type(4))) float float4_t;
typedef unsigned short u16;

__device__ __forceinline__ u16 f2bf(float f) {
    union { float f; unsigned u; } v; v.f = f;
    unsigned r = v.u + 0x7FFFu + ((v.u >> 16) & 1u);   // RNE
    return (u16)(r >> 16);
}
__device__ __forceinline__ float bf2f(u16 h) {
    union { unsigned u; float f; } v; v.u = ((unsigned)h) << 16;
    return v.f;
}
__device__ __forceinline__ void split4(float a, float b, float c, float d,
                                       short4_t* hi, short4_t* lo) {
    u16 h0 = f2bf(a), h1 = f2bf(b), h2 = f2bf(c), h3 = f2bf(d);
    (*hi)[0] = (short)h0; (*hi)[1] = (short)h1; (*hi)[2] = (short)h2; (*hi)[3] = (short)h3;
    (*lo)[0] = (short)f2bf(a - bf2f(h0));
    (*lo)[1] = (short)f2bf(b - bf2f(h1));
    (*lo)[2] = (short)f2bf(c - bf2f(h2));
    (*lo)[3] = (short)f2bf(d - bf2f(h3));
}

// async global->LDS, 16B per lane; LDS dest = wave-uniform base + lane*16.
__device__ __forceinline__ void gl_lds16(const void* g, void* l) {
    __builtin_amdgcn_global_load_lds(
        (const __attribute__((address_space(1))) unsigned int*)g,
        (__attribute__((address_space(3))) unsigned int*)l,
        16, 0, 0);
}

// ---------------------------------------------------------------------------
// Kernel 1: TRANSPOSED AP table, bf16.  APt[i][j] = AP[j][i]:
//   i even: sin(j * w_u), i odd: cos(j * w_u), u = i>>1, w_u = 10000^(-u/512).
// Transposed layout lets both consumers read AP with aligned b64 LDS reads
// (4 consecutive j for fixed i) instead of 8 scalar u16 reads per lane.
// ---------------------------------------------------------------------------
__global__ void apt_kernel(unsigned int* __restrict__ APtw) {
    int idx = blockIdx.x * 256 + threadIdx.x;   // 2,097,152 = 2048 rows * 1024 words
    int i = idx >> 10;             // row (feature index) 0..2047
    int jw = idx & 1023;           // word within row; j0 = 2*jw
    int u = i >> 1;
    float ex = exp2f(-(float)u * (13.287712379549449f / 512.0f));
    float a0 = (float)(2 * jw) * ex;
    float a1 = (float)(2 * jw + 1) * ex;
    float v0, v1;
    if (i & 1) { v0 = cosf(a0); v1 = cosf(a1); }
    else       { v0 = sinf(a0); v1 = sinf(a1); }
    APtw[(size_t)i * (N_ / 2) + jw] = (unsigned)f2bf(v0) | ((unsigned)f2bf(v1) << 16);
}

// ---------------------------------------------------------------------------
// Kernel 2: fp32 -> bf16 hi/lo pre-split of X, Wq|Wk (cat), Wv (hi), Wout (hi).
// ---------------------------------------------------------------------------
__global__ void split_kernel(const float* __restrict__ x,
                             const float* __restrict__ Wq, const float* __restrict__ Wk,
                             const float* __restrict__ Wv, const float* __restrict__ Wo,
                             u16* __restrict__ Xhi, u16* __restrict__ Xlo,
                             u16* __restrict__ Whi, u16* __restrict__ Wlo,
                             u16* __restrict__ Wvhi, u16* __restrict__ Wohi) {
    int i = blockIdx.x * 256 + threadIdx.x;            // 3,145,728 float4s
    const float* src; u16 *dhi, *dlo; size_t off;
    if (i < 2097152)      { src = x  + 4*(size_t)i;             dhi = Xhi;  dlo = Xlo;  off = 4*(size_t)i; }
    else if (i < 2359296) { size_t j = i - 2097152; src = Wq + 4*j; dhi = Whi; dlo = Wlo; off = 4*j; }
    else if (i < 2621440) { size_t j = i - 2359296; src = Wk + 4*j; dhi = Whi; dlo = Wlo; off = 1048576 + 4*j; }
    else if (i < 2883584) { size_t j = i - 2621440; src = Wv + 4*j; dhi = Wvhi; dlo = nullptr; off = 4*j; }
    else                  { size_t j = i - 2883584; src = Wo + 4*j; dhi = Wohi; dlo = nullptr; off = 4*j; }
    float4 v = *(const float4*)src;
    short4_t hi, lo;
    split4(v.x, v.y, v.z, v.w, &hi, &lo);
    *(short4_t*)(dhi + off) = hi;
    if (dlo) *(short4_t*)(dlo + off) = lo;
}

// ---------------------------------------------------------------------------
// Kernel 3: Q,K projections.  3-term bf16 split, m97 structure (unchanged).
// ---------------------------------------------------------------------------
__global__ __launch_bounds__(256, 4) void qk_gemm(
    const u16* __restrict__ Xhi, const u16* __restrict__ Xlo,
    const u16* __restrict__ Whi, const u16* __restrict__ Wlo,
    u16* __restrict__ Qhi, u16* __restrict__ Qlo,
    u16* __restrict__ Khi, u16* __restrict__ Klo)
{
    const int mt = blockIdx.x;   // 64
    const int nt = blockIdx.y;   // 16
    const int tid = threadIdx.x, wave = tid >> 6, lane = tid & 63;
    const int quad = lane >> 4, l16 = lane & 15;

    __shared__ __align__(16) u16 sA[2][128 * 32];
    __shared__ __align__(16) u16 sB[2][128 * 32];

    const int srow = lane >> 2;
    const int scol = (lane & 3) * 8;
    const size_t aoff = ((size_t)(mt * 128) + srow) * 1024 + scol;
    const size_t boff = ((size_t)(nt * 128) + srow) * 1024 + scol;
    const int r0 = wave * 16, r1 = 64 + wave * 16;

    float4_t acc[2][8];
#pragma unroll
    for (int i = 0; i < 2; ++i)
#pragma unroll
        for (int j = 0; j < 8; ++j) acc[i][j] = (float4_t)(0.f);

    for (int kt = 0; kt < 32; ++kt) {
        __syncthreads();
        const int kc0 = kt * 32;
        gl_lds16(Xhi + aoff + (size_t)r0 * 1024 + kc0, &sA[0][r0 * 32]);
        gl_lds16(Xhi + aoff + (size_t)r1 * 1024 + kc0, &sA[0][r1 * 32]);
        gl_lds16(Xlo + aoff + (size_t)r0 * 1024 + kc0, &sA[1][r0 * 32]);
        gl_lds16(Xlo + aoff + (size_t)r1 * 1024 + kc0, &sA[1][r1 * 32]);
        gl_lds16(Whi + boff + (size_t)r0 * 1024 + kc0, &sB[0][r0 * 32]);
        gl_lds16(Whi + boff + (size_t)r1 * 1024 + kc0, &sB[0][r1 * 32]);
        gl_lds16(Wlo + boff + (size_t)r0 * 1024 + kc0, &sB[1][r0 * 32]);
        gl_lds16(Wlo + boff + (size_t)r1 * 1024 + kc0, &sB[1][r1 * 32]);
        __syncthreads();

#pragma unroll
        for (int t = 0; t < 3; ++t) {
            const u16* As = sA[t == 2 ? 1 : 0];
            const u16* Bs = sB[t == 1 ? 1 : 0];
            short8 afr[2];
#pragma unroll
            for (int mi = 0; mi < 2; ++mi)
                afr[mi] = *(const short8*)(As + (wave * 32 + mi * 16 + l16) * 32 + quad * 8);
#pragma unroll
            for (int ne = 0; ne < 8; ++ne) {
                short8 bfr = *(const short8*)(Bs + (ne * 16 + l16) * 32 + quad * 8);
#pragma unroll
                for (int mi = 0; mi < 2; ++mi)
                    acc[mi][ne] = __builtin_amdgcn_mfma_f32_16x16x32_bf16(afr[mi], bfr, acc[mi][ne], 0, 0, 0);
            }
        }
    }

    const int b = mt >> 4, q0 = (mt & 15) * 128;
    const bool isQ = (nt < 8);
    u16* Hi = isQ ? Qhi : Khi;
    u16* Lo = isQ ? Qlo : Klo;
    const int h = isQ ? nt : nt - 8;
    const size_t base = (size_t)(b * 8 + h) * N_ * DH_;
#pragma unroll
    for (int mi = 0; mi < 2; ++mi)
#pragma unroll
        for (int ne = 0; ne < 8; ++ne)
#pragma unroll
            for (int r = 0; r < 4; ++r) {
                int q = q0 + wave * 32 + mi * 16 + quad * 4 + r;
                int e = ne * 16 + l16;
                float v = acc[mi][ne][r];
                u16 hv = f2bf(v);
                Hi[base + (size_t)q * DH_ + e] = hv;
                Lo[base + (size_t)q * DH_ + e] = f2bf(v - bf2f(hv));
            }
}

// ---------------------------------------------------------------------------
// Kernel 4: V^T[bh][e][q]  (1-term bf16, unchanged).
// ---------------------------------------------------------------------------
__global__ __launch_bounds__(256, 4) void v_gemm(
    const u16* __restrict__ Wvhi, const u16* __restrict__ Xhi,
    u16* __restrict__ VT)
{
    const int qt = blockIdx.x;   // 16
    const int bh = blockIdx.y;   // 32
    const int b = bh >> 3, h = bh & 7;
    const int tid = threadIdx.x, wave = tid >> 6, lane = tid & 63;
    const int quad = lane >> 4, l16 = lane & 15;

    __shared__ __align__(16) u16 sA[128 * 32];
    __shared__ __align__(16) u16 sB[128 * 32];

    const int srow = lane >> 2, scol = (lane & 3) * 8;
    const size_t aoff = ((size_t)(h * 128) + srow) * 1024 + scol;
    const size_t boff = ((size_t)(b * N_ + qt * 128) + srow) * 1024 + scol;
    const int r0 = wave * 16, r1 = 64 + wave * 16;

    float4_t acc[2][8];
#pragma unroll
    for (int i = 0; i < 2; ++i)
#pragma unroll
        for (int j = 0; j < 8; ++j) acc[i][j] = (float4_t)(0.f);

    for (int kt = 0; kt < 32; ++kt) {
        __syncthreads();
        const int kc0 = kt * 32;
        gl_lds16(Wvhi + aoff + (size_t)r0 * 1024 + kc0, &sA[r0 * 32]);
        gl_lds16(Wvhi + aoff + (size_t)r1 * 1024 + kc0, &sA[r1 * 32]);
        gl_lds16(Xhi  + boff + (size_t)r0 * 1024 + kc0, &sB[r0 * 32]);
        gl_lds16(Xhi  + boff + (size_t)r1 * 1024 + kc0, &sB[r1 * 32]);
        __syncthreads();

        short8 afr[2];
#pragma unroll
        for (int mi = 0; mi < 2; ++mi)
            afr[mi] = *(const short8*)(sA + (wave * 32 + mi * 16 + l16) * 32 + quad * 8);
#pragma unroll
        for (int ne = 0; ne < 8; ++ne) {
            short8 bfr = *(const short8*)(sB + (ne * 16 + l16) * 32 + quad * 8);
#pragma unroll
            for (int mi = 0; mi < 2; ++mi)
                acc[mi][ne] = __builtin_amdgcn_mfma_f32_16x16x32_bf16(afr[mi], bfr, acc[mi][ne], 0, 0, 0);
        }
    }

    u16* Cg = VT + (size_t)bh * DH_ * N_;
#pragma unroll
    for (int mi = 0; mi < 2; ++mi)
#pragma unroll
        for (int ne = 0; ne < 8; ++ne)
#pragma unroll
            for (int r = 0; r < 4; ++r) {
                int e = wave * 32 + mi * 16 + quad * 4 + r;
                int q = qt * 128 + ne * 16 + l16;
                Cg[(size_t)e * N_ + q] = f2bf(acc[mi][ne][r]);
            }
}

// ---------------------------------------------------------------------------
// Kernel 5 (pass A): l_j = sum_k exp(E[j,k]).  512 thr / 8 waves.
// Q FRAGMENTS IN REGISTERS (loop-invariant per wave): saves 96 b128 LDS
// reads/iter and deletes ldsQ (33.8 KB).  K-tiles of 64 + APt tile streamed
// with reg-prefetch dbuf; ONE barrier per iter.  kc-major MFMA chain with
// per-acc order (Qhi*Khi, Qlo*Khi, Qhi*Klo) — bitwise-matches attn MFMA1.
// ---------------------------------------------------------------------------
__global__ __launch_bounds__(512, 2) void rowstats_kernel(
    const u16* __restrict__ Qhi, const u16* __restrict__ Qlo,
    const u16* __restrict__ Khi, const u16* __restrict__ Klo,
    const u16* __restrict__ APt,
    const int* __restrict__ mask,
    float* __restrict__ lrow)
{
    const int jt = blockIdx.x;    // 32 j-tiles of 64
    const int bh = blockIdx.y;    // 32
    const int b = bh >> 3;
    const int tid = threadIdx.x, wave = tid >> 6, lane = tid & 63;
    const int quad = lane >> 4, l16 = lane & 15;
    const int jsub = (wave & 3) * 16, khalf = wave >> 2;

    __shared__ __align__(16) u16 ldsK[2][64 * 264];    // streamed, split (66 KB)
    __shared__ __align__(16) u16 ldsAPt[2][64 * 72];   // APt [i-local][j-local] (18 KB)
    __shared__ int   s_mk[2][64];
    __shared__ float psum[64 * 2];

    // Q fragments resident in registers (8 x short8 = 32 VGPR)
    short8 rQh[4], rQl[4];
    {
        const size_t qrow = ((size_t)bh * N_ + (size_t)(jt * 64 + jsub + l16)) * DH_;
#pragma unroll
        for (int kc = 0; kc < 4; ++kc) {
            rQh[kc] = *(const short8*)(Qhi + qrow + kc * 32 + quad * 8);
            rQl[kc] = *(const short8*)(Qlo + qrow + kc * 32 + quad * 8);
        }
    }

    // buf0: K tile 0 + APt tile 0 + mask
    {
        const size_t Kb = ((size_t)bh * N_) * DH_;
        for (int c = tid; c < 2048; c += 512) {
            int row = c >> 5, half = (c >> 4) & 1, seg = c & 15;
            *(short8*)(ldsK[0] + row * 264 + half * 128 + seg * 8) =
                *(const short8*)((half ? Klo : Khi) + Kb + (size_t)row * DH_ + seg * 8);
        }
        int irow = tid >> 3, jseg = tid & 7;
        *(short8*)(ldsAPt[0] + irow * 72 + jseg * 8) =
            *(const short8*)(APt + (size_t)irow * N_ + jt * 64 + jseg * 8);
        if (tid < 64) s_mk[0][tid] = mask[b * N_ + tid];
    }

    float p[4] = {0.f, 0.f, 0.f, 0.f};
    int mj_on[4];
#pragma unroll
    for (int r = 0; r < 4; ++r)
        mj_on[r] = mask[b * N_ + jt * 64 + jsub + quad * 4 + r];

    __syncthreads();

    for (int kt = 0; kt < 32; ++kt) {
        const int cur = kt & 1, nxt = cur ^ 1;
        short8 rK[4], rAP;
        int rmk = 0;
        if (kt < 31) {
            const size_t Kb2 = ((size_t)bh * N_ + (size_t)(kt + 1) * 64) * DH_;
#pragma unroll
            for (int i = 0; i < 4; ++i) {
                int c = tid + i * 512;
                int row = c >> 5, half = (c >> 4) & 1, seg = c & 15;
                rK[i] = *(const short8*)((half ? Klo : Khi) + Kb2 + (size_t)row * DH_ + seg * 8);
            }
            int irow = tid >> 3, jseg = tid & 7;
            rAP = *(const short8*)(APt + (size_t)((kt + 1) * 64 + irow) * N_ + jt * 64 + jseg * 8);
            if (tid < 64) rmk = mask[b * N_ + (kt + 1) * 64 + tid];
        }

        // MFMA: S[16 j][32 k per wave], kc-major, K-hi frags reused for t0/t2
        float4_t acc[2];
        acc[0] = (float4_t)(0.f); acc[1] = (float4_t)(0.f);
#pragma unroll
        for (int kc = 0; kc < 4; ++kc) {
            short8 bH[2], bL[2];
#pragma unroll
            for (int nk = 0; nk < 2; ++nk)
                bH[nk] = *(const short8*)(ldsK[cur] + (khalf * 32 + nk * 16 + l16) * 264 + kc * 32 + quad * 8);
#pragma unroll
            for (int nk = 0; nk < 2; ++nk)
                acc[nk] = __builtin_amdgcn_mfma_f32_16x16x32_bf16(rQh[kc], bH[nk], acc[nk], 0, 0, 0);
#pragma unroll
            for (int nk = 0; nk < 2; ++nk)
                acc[nk] = __builtin_amdgcn_mfma_f32_16x16x32_bf16(rQl[kc], bH[nk], acc[nk], 0, 0, 0);
#pragma unroll
            for (int nk = 0; nk < 2; ++nk)
                bL[nk] = *(const short8*)(ldsK[cur] + (khalf * 32 + nk * 16 + l16) * 264 + 128 + kc * 32 + quad * 8);
#pragma unroll
            for (int nk = 0; nk < 2; ++nk)
                acc[nk] = __builtin_amdgcn_mfma_f32_16x16x32_bf16(rQh[kc], bL[nk], acc[nk], 0, 0, 0);
        }

#pragma unroll
        for (int nk = 0; nk < 2; ++nk) {
            int kk = khalf * 32 + nk * 16 + l16;
            short4_t ap4 = *(const short4_t*)(ldsAPt[cur] + kk * 72 + jsub + quad * 4);
            int mk = s_mk[cur][kk];
#pragma unroll
            for (int r = 0; r < 4; ++r) {
                float e = acc[nk][r] + bf2f((u16)ap4[r]);
                e = (mj_on[r] && mk) ? e : -1.0e9f;
                p[r] += __expf(e);
            }
        }

        if (kt < 31) {
#pragma unroll
            for (int i = 0; i < 4; ++i) {
                int c = tid + i * 512;
                int row = c >> 5, half = (c >> 4) & 1, seg = c & 15;
                *(short8*)(ldsK[nxt] + row * 264 + half * 128 + seg * 8) = rK[i];
            }
            int irow = tid >> 3, jseg = tid & 7;
            *(short8*)(ldsAPt[nxt] + irow * 72 + jseg * 8) = rAP;
            if (tid < 64) s_mk[nxt][tid] = rmk;
        }
        __syncthreads();
    }

    // reduce over l16 lanes, then over the two k-half waves
#pragma unroll
    for (int r = 0; r < 4; ++r) {
        float s = p[r];
        for (int off = 1; off < 16; off <<= 1)
            s += __shfl_xor(s, off, 64);
        if (l16 == 0)
            psum[(jsub + quad * 4 + r) * 2 + khalf] = s;
    }
    __syncthreads();
    if (tid < 64)
        lrow[(size_t)bh * N_ + jt * 64 + tid] = psum[tid * 2] + psum[tid * 2 + 1];
}

// ---------------------------------------------------------------------------
// Kernel 6 (pass B): y[i,e] = sum_j A[j,i] V[j,e], A = exp(E)/l_j.
// 512 thr / 8 waves.  K FRAGMENTS IN REGISTERS (loop-invariant per wave):
// deletes ldsK (67.6 KB) and its 96 b128 reads/iter.  MFMA1 is kc-major with
// Q-hi frag caching (24->16 reads/wave).  MFMA2 retiled to 4 i-pods x 2
// e-halves (V-frag reuse x2).  APt read as aligned b64.  h==7 stores A.
// ---------------------------------------------------------------------------
__global__ __launch_bounds__(512, 2) void attn_kernel(
    const u16* __restrict__ Qhi, const u16* __restrict__ Qlo,
    const u16* __restrict__ Khi, const u16* __restrict__ Klo,
    const u16* __restrict__ VT,
    const u16* __restrict__ APt,
    const int* __restrict__ mask,
    const float* __restrict__ lrow,
    u16* __restrict__ yout,               // [BS,N,D] bf16 (ws)
    float* __restrict__ aout)             // [BS,N,N] fp32 (d_out tail)
{
    const int it = blockIdx.x;   // 16 i-tiles (keys)
    const int bh = blockIdx.y;   // 32
    const int b = bh >> 3, h = bh & 7;
    const int tid = threadIdx.x, wave = tid >> 6, lane = tid & 63;  // 8 waves
    const int quad = lane >> 4, l16 = lane & 15;

    __shared__ __align__(16) u16 ldsQ[2][32 * 264];    // Q_j split, dbuf     (33.8 KB)
    __shared__ __align__(16) u16 ldsV[2][128 * 40];    // V^T [e][j], dbuf    (20.5 KB)
    __shared__ __align__(16) u16 ldsAPt[2][128 * 40];  // APt [i][j], dbuf    (20.5 KB)
    __shared__ __align__(16) u16 ldsA[128 * 40];       // A^T [i][j]          (10.2 KB)
    __shared__ float s_il[2][32];
    __shared__ int   s_dead[2][32];
    __shared__ int   s_mj[2][32];

    const int i_local = wave * 16 + l16;
    const int ig = it * 128 + i_local;

    // K fragments resident in registers (8 x short8 = 32 VGPR)
    short8 rKh[4], rKl[4];
    {
        const size_t krow = ((size_t)bh * N_ + ig) * DH_;
#pragma unroll
        for (int kc = 0; kc < 4; ++kc) {
            rKh[kc] = *(const short8*)(Khi + krow + kc * 32 + quad * 8);
            rKl[kc] = *(const short8*)(Klo + krow + kc * 32 + quad * 8);
        }
    }

    // buf0 (jt = 0)
    {
        const size_t Qb0 = ((size_t)bh * N_) * DH_;
        for (int c = tid; c < 1024; c += 512) {
            int row = c >> 5, half = (c >> 4) & 1, seg = c & 15;
            *(short8*)(ldsQ[0] + row * 264 + half * 128 + seg * 8) =
                *(const short8*)((half ? Qlo : Qhi) + Qb0 + (size_t)row * DH_ + seg * 8);
        }
        { int e = tid >> 2, seg = tid & 3;
          *(short8*)(ldsV[0] + e * 40 + seg * 8) =
              *(const short8*)(VT + (size_t)bh * DH_ * N_ + (size_t)e * N_ + seg * 8); }
        { int irow = tid >> 2, jseg = tid & 3;
          *(short8*)(ldsAPt[0] + irow * 40 + jseg * 8) =
              *(const short8*)(APt + (size_t)(it * 128 + irow) * N_ + jseg * 8); }
        if (tid < 32) {
            float l = lrow[(size_t)bh * N_ + tid];
            int mj = mask[b * N_ + tid];
            int alive = (mj != 0) && (l > 0.f);
            s_il[0][tid] = alive ? 1.0f / l : 0.f;
            s_dead[0][tid] = !alive;
            s_mj[0][tid] = mj;
        }
    }

    const int ion = mask[b * N_ + ig];
    const int ip = wave >> 1, eh = wave & 1;   // MFMA2 retile: 4 i-pods x 2 e-halves

    float4_t accy[2][4];   // [ni][ne]: i = ip*32+ni*16.., e = eh*64+ne*16..
#pragma unroll
    for (int ni = 0; ni < 2; ++ni)
#pragma unroll
        for (int ne = 0; ne < 4; ++ne) accy[ni][ne] = (float4_t)(0.f);

    const bool do_aout = (h == 7);
    const float inv_n = 1.0f / (float)N_;

    __syncthreads();

    for (int jt = 0; jt < 64; ++jt) {
        const int cur = jt & 1, nxt = cur ^ 1;
        const int j0 = jt * 32;

        // prefetch next j-tile into registers (hidden under MFMA1+epi+MFMA2)
        short8 rQ[2], rV, rAP;
        float r_il = 0.f; int r_dead = 0, r_mj = 0;
        if (jt < 63) {
            const int j0n = j0 + 32;
            const size_t Qb2 = ((size_t)bh * N_ + j0n) * DH_;
#pragma unroll
            for (int i = 0; i < 2; ++i) {
                int c = tid + i * 512;
                int row = c >> 5, half = (c >> 4) & 1, seg = c & 15;
                rQ[i] = *(const short8*)((half ? Qlo : Qhi) + Qb2 + (size_t)row * DH_ + seg * 8);
            }
            { int e = tid >> 2, seg = tid & 3;
              rV = *(const short8*)(VT + (size_t)bh * DH_ * N_ + (size_t)e * N_ + j0n + seg * 8); }
            { int irow = tid >> 2, jseg = tid & 3;
              rAP = *(const short8*)(APt + (size_t)(it * 128 + irow) * N_ + j0n + jseg * 8); }
            if (tid < 32) {
                float l = lrow[(size_t)bh * N_ + j0n + tid];
                r_mj = mask[b * N_ + j0n + tid];
                int alive = (r_mj != 0) && (l > 0.f);
                r_il = alive ? 1.0f / l : 0.f;
                r_dead = !alive;
            }
        }

        // MFMA1: S[j(32), i(16 per wave)] — kc-major, per-acc order
        // (Qhi*Khi, Qlo*Khi, Qhi*Klo) bitwise-matches rowstats
        float4_t accs[2];
        accs[0] = (float4_t)(0.f); accs[1] = (float4_t)(0.f);
#pragma unroll
        for (int kc = 0; kc < 4; ++kc) {
            short8 aH[2], aL[2];
#pragma unroll
            for (int mj = 0; mj < 2; ++mj)
                aH[mj] = *(const short8*)(ldsQ[cur] + (mj * 16 + l16) * 264 + kc * 32 + quad * 8);
#pragma unroll
            for (int mj = 0; mj < 2; ++mj)
                accs[mj] = __builtin_amdgcn_mfma_f32_16x16x32_bf16(aH[mj], rKh[kc], accs[mj], 0, 0, 0);
#pragma unroll
            for (int mj = 0; mj < 2; ++mj)
                aL[mj] = *(const short8*)(ldsQ[cur] + (mj * 16 + l16) * 264 + 128 + kc * 32 + quad * 8);
#pragma unroll
            for (int mj = 0; mj < 2; ++mj)
                accs[mj] = __builtin_amdgcn_mfma_f32_16x16x32_bf16(aL[mj], rKh[kc], accs[mj], 0, 0, 0);
#pragma unroll
            for (int mj = 0; mj < 2; ++mj)
                accs[mj] = __builtin_amdgcn_mfma_f32_16x16x32_bf16(aH[mj], rKl[kc], accs[mj], 0, 0, 0);
        }

        // A = exp(E)*il (dead row -> 1/N); write A^T to LDS; h==7: fp32 out
#pragma unroll
        for (int mj = 0; mj < 2; ++mj) {
            short4_t ap4 = *(const short4_t*)(ldsAPt[cur] + i_local * 40 + mj * 16 + quad * 4);
            short4_t pk;
#pragma unroll
            for (int r = 0; r < 4; ++r) {
                int jl = mj * 16 + quad * 4 + r;
                float e = accs[mj][r] + bf2f((u16)ap4[r]);
                e = (s_mj[cur][jl] && ion) ? e : -1.0e9f;
                float a = s_dead[cur][jl] ? inv_n : __expf(e) * s_il[cur][jl];
                pk[r] = (short)f2bf(a);
                if (do_aout)
                    aout[((size_t)(b * N_ + j0 + jl)) * N_ + ig] = a;
            }
            *(short4_t*)(ldsA + (size_t)i_local * 40 + mj * 16 + quad * 4) = pk;
        }
        __syncthreads();   // B1: ldsA ready; reads of ldsQ/ldsAPt[cur] done

        // MFMA2: y[i(32 per pod), e(64 per half)] += A^T · V   (k = 32)
        {
            short8 afrA[2];
#pragma unroll
            for (int ni = 0; ni < 2; ++ni)
                afrA[ni] = *(const short8*)(ldsA + (ip * 32 + ni * 16 + l16) * 40 + quad * 8);
#pragma unroll
            for (int ne = 0; ne < 4; ++ne) {
                short8 bfr = *(const short8*)(ldsV[cur] + (eh * 64 + ne * 16 + l16) * 40 + quad * 8);
#pragma unroll
                for (int ni = 0; ni < 2; ++ni)
                    accy[ni][ne] = __builtin_amdgcn_mfma_f32_16x16x32_bf16(afrA[ni], bfr, accy[ni][ne], 0, 0, 0);
            }
        }

        if (jt < 63) {
#pragma unroll
            for (int i = 0; i < 2; ++i) {
                int c = tid + i * 512;
                int row = c >> 5, half = (c >> 4) & 1, seg = c & 15;
                *(short8*)(ldsQ[nxt] + row * 264 + half * 128 + seg * 8) = rQ[i];
            }
            { int e = tid >> 2, seg = tid & 3;
              *(short8*)(ldsV[nxt] + e * 40 + seg * 8) = rV; }
            { int irow = tid >> 2, jseg = tid & 3;
              *(short8*)(ldsAPt[nxt] + irow * 40 + jseg * 8) = rAP; }
            if (tid < 32) {
                s_il[nxt][tid] = r_il;
                s_dead[nxt][tid] = r_dead;
                s_mj[nxt][tid] = r_mj;
            }
        }
        __syncthreads();   // B2: buf[nxt] ready; ldsA reads done
    }

#pragma unroll
    for (int ni = 0; ni < 2; ++ni)
#pragma unroll
        for (int ne = 0; ne < 4; ++ne)
#pragma unroll
            for (int r = 0; r < 4; ++r) {
                int irow = ip * 32 + ni * 16 + quad * 4 + r;
                int e = eh * 64 + ne * 16 + l16;
                yout[((size_t)b * N_ + it * 128 + irow) * D_ + h * DH_ + e] =
                    f2bf(accy[ni][ne][r]);
            }
}

// ---------------------------------------------------------------------------
// Kernel 7: out[m,o] = sum_d y[m,d] Wout[o,d]  (unchanged).
// ---------------------------------------------------------------------------
__global__ __launch_bounds__(256, 4) void outgemm_kernel(
    const u16* __restrict__ A,     // y   [8192][1024] bf16
    const u16* __restrict__ B,     // Wout[1024][1024] bf16 (hi)
    float* __restrict__ C)         // out [8192][1024] fp32
{
    const int nt = blockIdx.x;   // 8
    const int mt = blockIdx.y;   // 64
    const int tid = threadIdx.x, wave = tid >> 6, lane = tid & 63;
    const int quad = lane >> 4, l16 = lane & 15;

    __shared__ __align__(16) u16 sA[128 * 32];
    __shared__ __align__(16) u16 sB[128 * 32];

    const int srow = lane >> 2, scol = (lane & 3) * 8;
    const size_t aoff = ((size_t)(mt * 128) + srow) * 1024 + scol;
    const size_t boff = ((size_t)(nt * 128) + srow) * 1024 + scol;
    const int r0 = wave * 16, r1 = 64 + wave * 16;

    float4_t acc[2][8];
#pragma unroll
    for (int i = 0; i < 2; ++i)
#pragma unroll
        for (int j = 0; j < 8; ++j) acc[i][j] = (float4_t)(0.f);

    for (int kt = 0; kt < 32; ++kt) {
        __syncthreads();
        const int kc0 = kt * 32;
        gl_lds16(A + aoff + (size_t)r0 * 1024 + kc0, &sA[r0 * 32]);
        gl_lds16(A + aoff + (size_t)r1 * 1024 + kc0, &sA[r1 * 32]);
        gl_lds16(B + boff + (size_t)r0 * 1024 + kc0, &sB[r0 * 32]);
        gl_lds16(B + boff + (size_t)r1 * 1024 + kc0, &sB[r1 * 32]);
        __syncthreads();

        short8 afr[2];
#pragma unroll
        for (int mi = 0; mi < 2; ++mi)
            afr[mi] = *(const short8*)(sA + (wave * 32 + mi * 16 + l16) * 32 + quad * 8);
#pragma unroll
        for (int ne = 0; ne < 8; ++ne) {
            short8 bfr = *(const short8*)(sB + (ne * 16 + l16) * 32 + quad * 8);
#pragma unroll
            for (int mi = 0; mi < 2; ++mi)
                acc[mi][ne] = __builtin_amdgcn_mfma_f32_16x16x32_bf16(afr[mi], bfr, acc[mi][ne], 0, 0, 0);
        }
    }

#pragma unroll
    for (int mi = 0; mi < 2; ++mi)
#pragma unroll
        for (int ne = 0; ne < 8; ++ne)
#pragma unroll
            for (int r = 0; r < 4; ++r) {
                int row = mt * 128 + wave * 32 + mi * 16 + quad * 4 + r;
                int col = nt * 128 + ne * 16 + l16;
                C[(size_t)row * D_ + col] = acc[mi][ne][r];
            }
}

// ---------------------------------------------------------------------------
extern "C" void kernel_launch(void* const* d_in, const int* in_sizes, int n_in,
                              void* d_out, int out_size, void* d_ws, size_t ws_size,
                              hipStream_t stream)
{
    const float* x   = (const float*)d_in[0];
    const int*   msk = (const int*)d_in[1];
    const float* Wq  = (const float*)d_in[2];
    const float* Wk  = (const float*)d_in[3];
    const float* Wv  = (const float*)d_in[4];
    const float* Wo  = (const float*)d_in[5];

    float* out  = (float*)d_out;                         // [4,2048,1024] fp32
    float* aout = out + (size_t)BS_ * N_ * D_;           // [4,2048,2048] fp32

    // transient split buffers in d_out (dead before attn/outgemm overwrite)
    u16* Whi  = (u16*)d_out;                       // 2048*1024
    u16* Wlo  = Whi  + (size_t)2048 * 1024;        // 2048*1024
    u16* Wvhi = Wlo  + (size_t)2048 * 1024;        // 1024*1024
    u16* Xhi  = Wvhi + (size_t)1024 * 1024;        // 8192*1024
    u16* Xlo  = Xhi  + (size_t)8192 * 1024;        // 8192*1024

    // workspace (111.4 MB)
    char* w = (char*)d_ws;
    u16* APt = (u16*)w;                       w += (size_t)N_ * N_ * 2;   // transposed AP
    const size_t szqk = (size_t)BS_ * H_ * N_ * DH_ * 2;
    u16* Qhi = (u16*)w; w += szqk;
    u16* Qlo = (u16*)w; w += szqk;
    u16* Khi = (u16*)w; w += szqk;
    u16* Klo = (u16*)w; w += szqk;
    u16* VT  = (u16*)w; w += szqk;
    float* lrow = (float*)w;                  w += (size_t)BS_ * H_ * N_ * 4;
    u16* Wohi = (u16*)w;                      w += (size_t)D_ * D_ * 2;
    u16* yb   = (u16*)w;                      w += (size_t)BS_ * N_ * D_ * 2;

    apt_kernel<<<8192, 256, 0, stream>>>((unsigned int*)APt);
    split_kernel<<<12288, 256, 0, stream>>>(x, Wq, Wk, Wv, Wo,
                                            Xhi, Xlo, Whi, Wlo, Wvhi, Wohi);
    qk_gemm<<<dim3(64, 16), 256, 0, stream>>>(Xhi, Xlo, Whi, Wlo,
                                              Qhi, Qlo, Khi, Klo);
    v_gemm<<<dim3(16, 32), 256, 0, stream>>>(Wvhi, Xhi, VT);
    rowstats_kernel<<<dim3(32, 32), 512, 0, stream>>>(Qhi, Qlo, Khi, Klo, APt, msk, lrow);
    attn_kernel<<<dim3(16, 32), 512, 0, stream>>>(Qhi, Qlo, Khi, Klo, VT, APt, msk,
                                                  lrow, yb, aout);
    outgemm_kernel<<<dim3(8, 64), 256, 0, stream>>>(yb, Wohi, out);
}

// Round 2
// 683.098 us; speedup vs baseline: 1.2055x; 1.0461x over previous
//
#include <hip/hip_runtime.h>
#include <math.h>

// Problem constants
#define BS_ 4
#define N_  2048
#define D_  1024
#define H_  8
#define DH_ 128

typedef __attribute__((ext_vector_type(8))) short short8;
typedef __attribute__((ext_vector_type(4))) short short4_t;
typedef __attribute__((ext_vector_type(4))) float float4_t;
typedef unsigned short u16;

__device__ __forceinline__ u16 f2bf(float f) {
    union { float f; unsigned u; } v; v.f = f;
    unsigned r = v.u + 0x7FFFu + ((v.u >> 16) & 1u);   // RNE
    return (u16)(r >> 16);
}
__device__ __forceinline__ float bf2f(u16 h) {
    union { unsigned u; float f; } v; v.u = ((unsigned)h) << 16;
    return v.f;
}
__device__ __forceinline__ void split4(float a, float b, float c, float d,
                                       short4_t* hi, short4_t* lo) {
    u16 h0 = f2bf(a), h1 = f2bf(b), h2 = f2bf(c), h3 = f2bf(d);
    (*hi)[0] = (short)h0; (*hi)[1] = (short)h1; (*hi)[2] = (short)h2; (*hi)[3] = (short)h3;
    (*lo)[0] = (short)f2bf(a - bf2f(h0));
    (*lo)[1] = (short)f2bf(b - bf2f(h1));
    (*lo)[2] = (short)f2bf(c - bf2f(h2));
    (*lo)[3] = (short)f2bf(d - bf2f(h3));
}

// async global->LDS, 16B per lane; LDS dest = wave-uniform base + lane*16.
__device__ __forceinline__ void gl_lds16(const void* g, void* l) {
    __builtin_amdgcn_global_load_lds(
        (const __attribute__((address_space(1))) unsigned int*)g,
        (__attribute__((address_space(3))) unsigned int*)l,
        16, 0, 0);
}

// ---------------------------------------------------------------------------
// Kernel 1: TRANSPOSED AP table, bf16.  APt[i][j] = AP[j][i]:
//   i even: sin(j * w_u), i odd: cos(j * w_u), u = i>>1, w_u = 10000^(-u/512).
// ---------------------------------------------------------------------------
__global__ void apt_kernel(unsigned int* __restrict__ APtw) {
    int idx = blockIdx.x * 256 + threadIdx.x;   // 2,097,152 = 2048 rows * 1024 words
    int i = idx >> 10;             // row (feature index) 0..2047
    int jw = idx & 1023;           // word within row; j0 = 2*jw
    int u = i >> 1;
    float ex = exp2f(-(float)u * (13.287712379549449f / 512.0f));
    float a0 = (float)(2 * jw) * ex;
    float a1 = (float)(2 * jw + 1) * ex;
    float v0, v1;
    if (i & 1) { v0 = cosf(a0); v1 = cosf(a1); }
    else       { v0 = sinf(a0); v1 = sinf(a1); }
    APtw[(size_t)i * (N_ / 2) + jw] = (unsigned)f2bf(v0) | ((unsigned)f2bf(v1) << 16);
}

// ---------------------------------------------------------------------------
// Kernel 2: fp32 -> bf16 hi/lo pre-split of X, Wq|Wk (cat), Wv (hi), Wout (hi).
// ---------------------------------------------------------------------------
__global__ void split_kernel(const float* __restrict__ x,
                             const float* __restrict__ Wq, const float* __restrict__ Wk,
                             const float* __restrict__ Wv, const float* __restrict__ Wo,
                             u16* __restrict__ Xhi, u16* __restrict__ Xlo,
                             u16* __restrict__ Whi, u16* __restrict__ Wlo,
                             u16* __restrict__ Wvhi, u16* __restrict__ Wohi) {
    int i = blockIdx.x * 256 + threadIdx.x;            // 3,145,728 float4s
    const float* src; u16 *dhi, *dlo; size_t off;
    if (i < 2097152)      { src = x  + 4*(size_t)i;             dhi = Xhi;  dlo = Xlo;  off = 4*(size_t)i; }
    else if (i < 2359296) { size_t j = i - 2097152; src = Wq + 4*j; dhi = Whi; dlo = Wlo; off = 4*j; }
    else if (i < 2621440) { size_t j = i - 2359296; src = Wk + 4*j; dhi = Whi; dlo = Wlo; off = 1048576 + 4*j; }
    else if (i < 2883584) { size_t j = i - 2621440; src = Wv + 4*j; dhi = Wvhi; dlo = nullptr; off = 4*j; }
    else                  { size_t j = i - 2883584; src = Wo + 4*j; dhi = Wohi; dlo = nullptr; off = 4*j; }
    float4 v = *(const float4*)src;
    short4_t hi, lo;
    split4(v.x, v.y, v.z, v.w, &hi, &lo);
    *(short4_t*)(dhi + off) = hi;
    if (dlo) *(short4_t*)(dlo + off) = lo;
}

// ---------------------------------------------------------------------------
// Kernel 3: Q,K projections.  3-term bf16 split, m97 structure (unchanged).
// ---------------------------------------------------------------------------
__global__ __launch_bounds__(256, 4) void qk_gemm(
    const u16* __restrict__ Xhi, const u16* __restrict__ Xlo,
    const u16* __restrict__ Whi, const u16* __restrict__ Wlo,
    u16* __restrict__ Qhi, u16* __restrict__ Qlo,
    u16* __restrict__ Khi, u16* __restrict__ Klo)
{
    const int mt = blockIdx.x;   // 64
    const int nt = blockIdx.y;   // 16
    const int tid = threadIdx.x, wave = tid >> 6, lane = tid & 63;
    const int quad = lane >> 4, l16 = lane & 15;

    __shared__ __align__(16) u16 sA[2][128 * 32];
    __shared__ __align__(16) u16 sB[2][128 * 32];

    const int srow = lane >> 2;
    const int scol = (lane & 3) * 8;
    const size_t aoff = ((size_t)(mt * 128) + srow) * 1024 + scol;
    const size_t boff = ((size_t)(nt * 128) + srow) * 1024 + scol;
    const int r0 = wave * 16, r1 = 64 + wave * 16;

    float4_t acc[2][8];
#pragma unroll
    for (int i = 0; i < 2; ++i)
#pragma unroll
        for (int j = 0; j < 8; ++j) acc[i][j] = (float4_t)(0.f);

    for (int kt = 0; kt < 32; ++kt) {
        __syncthreads();
        const int kc0 = kt * 32;
        gl_lds16(Xhi + aoff + (size_t)r0 * 1024 + kc0, &sA[0][r0 * 32]);
        gl_lds16(Xhi + aoff + (size_t)r1 * 1024 + kc0, &sA[0][r1 * 32]);
        gl_lds16(Xlo + aoff + (size_t)r0 * 1024 + kc0, &sA[1][r0 * 32]);
        gl_lds16(Xlo + aoff + (size_t)r1 * 1024 + kc0, &sA[1][r1 * 32]);
        gl_lds16(Whi + boff + (size_t)r0 * 1024 + kc0, &sB[0][r0 * 32]);
        gl_lds16(Whi + boff + (size_t)r1 * 1024 + kc0, &sB[0][r1 * 32]);
        gl_lds16(Wlo + boff + (size_t)r0 * 1024 + kc0, &sB[1][r0 * 32]);
        gl_lds16(Wlo + boff + (size_t)r1 * 1024 + kc0, &sB[1][r1 * 32]);
        __syncthreads();

#pragma unroll
        for (int t = 0; t < 3; ++t) {
            const u16* As = sA[t == 2 ? 1 : 0];
            const u16* Bs = sB[t == 1 ? 1 : 0];
            short8 afr[2];
#pragma unroll
            for (int mi = 0; mi < 2; ++mi)
                afr[mi] = *(const short8*)(As + (wave * 32 + mi * 16 + l16) * 32 + quad * 8);
#pragma unroll
            for (int ne = 0; ne < 8; ++ne) {
                short8 bfr = *(const short8*)(Bs + (ne * 16 + l16) * 32 + quad * 8);
#pragma unroll
                for (int mi = 0; mi < 2; ++mi)
                    acc[mi][ne] = __builtin_amdgcn_mfma_f32_16x16x32_bf16(afr[mi], bfr, acc[mi][ne], 0, 0, 0);
            }
        }
    }

    const int b = mt >> 4, q0 = (mt & 15) * 128;
    const bool isQ = (nt < 8);
    u16* Hi = isQ ? Qhi : Khi;
    u16* Lo = isQ ? Qlo : Klo;
    const int h = isQ ? nt : nt - 8;
    const size_t base = (size_t)(b * 8 + h) * N_ * DH_;
#pragma unroll
    for (int mi = 0; mi < 2; ++mi)
#pragma unroll
        for (int ne = 0; ne < 8; ++ne)
#pragma unroll
            for (int r = 0; r < 4; ++r) {
                int q = q0 + wave * 32 + mi * 16 + quad * 4 + r;
                int e = ne * 16 + l16;
                float v = acc[mi][ne][r];
                u16 hv = f2bf(v);
                Hi[base + (size_t)q * DH_ + e] = hv;
                Lo[base + (size_t)q * DH_ + e] = f2bf(v - bf2f(hv));
            }
}

// ---------------------------------------------------------------------------
// Kernel 4: V^T[bh][e][q]  (1-term bf16, unchanged).
// ---------------------------------------------------------------------------
__global__ __launch_bounds__(256, 4) void v_gemm(
    const u16* __restrict__ Wvhi, const u16* __restrict__ Xhi,
    u16* __restrict__ VT)
{
    const int qt = blockIdx.x;   // 16
    const int bh = blockIdx.y;   // 32
    const int b = bh >> 3, h = bh & 7;
    const int tid = threadIdx.x, wave = tid >> 6, lane = tid & 63;
    const int quad = lane >> 4, l16 = lane & 15;

    __shared__ __align__(16) u16 sA[128 * 32];
    __shared__ __align__(16) u16 sB[128 * 32];

    const int srow = lane >> 2, scol = (lane & 3) * 8;
    const size_t aoff = ((size_t)(h * 128) + srow) * 1024 + scol;
    const size_t boff = ((size_t)(b * N_ + qt * 128) + srow) * 1024 + scol;
    const int r0 = wave * 16, r1 = 64 + wave * 16;

    float4_t acc[2][8];
#pragma unroll
    for (int i = 0; i < 2; ++i)
#pragma unroll
        for (int j = 0; j < 8; ++j) acc[i][j] = (float4_t)(0.f);

    for (int kt = 0; kt < 32; ++kt) {
        __syncthreads();
        const int kc0 = kt * 32;
        gl_lds16(Wvhi + aoff + (size_t)r0 * 1024 + kc0, &sA[r0 * 32]);
        gl_lds16(Wvhi + aoff + (size_t)r1 * 1024 + kc0, &sA[r1 * 32]);
        gl_lds16(Xhi  + boff + (size_t)r0 * 1024 + kc0, &sB[r0 * 32]);
        gl_lds16(Xhi  + boff + (size_t)r1 * 1024 + kc0, &sB[r1 * 32]);
        __syncthreads();

        short8 afr[2];
#pragma unroll
        for (int mi = 0; mi < 2; ++mi)
            afr[mi] = *(const short8*)(sA + (wave * 32 + mi * 16 + l16) * 32 + quad * 8);
#pragma unroll
        for (int ne = 0; ne < 8; ++ne) {
            short8 bfr = *(const short8*)(sB + (ne * 16 + l16) * 32 + quad * 8);
#pragma unroll
            for (int mi = 0; mi < 2; ++mi)
                acc[mi][ne] = __builtin_amdgcn_mfma_f32_16x16x32_bf16(afr[mi], bfr, acc[mi][ne], 0, 0, 0);
        }
    }

    u16* Cg = VT + (size_t)bh * DH_ * N_;
#pragma unroll
    for (int mi = 0; mi < 2; ++mi)
#pragma unroll
        for (int ne = 0; ne < 8; ++ne)
#pragma unroll
            for (int r = 0; r < 4; ++r) {
                int e = wave * 32 + mi * 16 + quad * 4 + r;
                int q = qt * 128 + ne * 16 + l16;
                Cg[(size_t)e * N_ + q] = f2bf(acc[mi][ne][r]);
            }
}

// ---------------------------------------------------------------------------
// Kernel 5 (pass A): l_j = sum_k exp(E[j,k]).  512 thr / 8 waves.
// Q frags in registers.  AP now loaded PER-LANE FROM GLOBAL (8B x2, 1-iter
// reg prefetch) -> ldsAPt deleted -> LDS 68.6 KB -> 2 blocks/CU resident.
// ---------------------------------------------------------------------------
__global__ __launch_bounds__(512, 4) void rowstats_kernel(
    const u16* __restrict__ Qhi, const u16* __restrict__ Qlo,
    const u16* __restrict__ Khi, const u16* __restrict__ Klo,
    const u16* __restrict__ APt,
    const int* __restrict__ mask,
    float* __restrict__ lrow)
{
    const int jt = blockIdx.x;    // 32 j-tiles of 64
    const int bh = blockIdx.y;    // 32
    const int b = bh >> 3;
    const int tid = threadIdx.x, wave = tid >> 6, lane = tid & 63;
    const int quad = lane >> 4, l16 = lane & 15;
    const int jsub = (wave & 3) * 16, khalf = wave >> 2;

    __shared__ __align__(16) u16 ldsK[2][64 * 264];    // streamed, split (66 KB)
    __shared__ int   s_mk[2][64];
    __shared__ float psum[64 * 2];

    // Q fragments resident in registers (8 x short8 = 32 VGPR)
    short8 rQh[4], rQl[4];
    {
        const size_t qrow = ((size_t)bh * N_ + (size_t)(jt * 64 + jsub + l16)) * DH_;
#pragma unroll
        for (int kc = 0; kc < 4; ++kc) {
            rQh[kc] = *(const short8*)(Qhi + qrow + kc * 32 + quad * 8);
            rQl[kc] = *(const short8*)(Qlo + qrow + kc * 32 + quad * 8);
        }
    }

    // per-lane AP base: row = key index (khalf*32 + nk*16 + l16), col fixed
    const u16* ap_base = APt + (size_t)(khalf * 32 + l16) * N_ + jt * 64 + jsub + quad * 4;
    short4_t apc[2];
#pragma unroll
    for (int nk = 0; nk < 2; ++nk)
        apc[nk] = *(const short4_t*)(ap_base + (size_t)(nk * 16) * N_);

    // buf0: K tile 0 + mask
    {
        const size_t Kb = ((size_t)bh * N_) * DH_;
        for (int c = tid; c < 2048; c += 512) {
            int row = c >> 5, half = (c >> 4) & 1, seg = c & 15;
            *(short8*)(ldsK[0] + row * 264 + half * 128 + seg * 8) =
                *(const short8*)((half ? Klo : Khi) + Kb + (size_t)row * DH_ + seg * 8);
        }
        if (tid < 64) s_mk[0][tid] = mask[b * N_ + tid];
    }

    float p[4] = {0.f, 0.f, 0.f, 0.f};
    int mj_on[4];
#pragma unroll
    for (int r = 0; r < 4; ++r)
        mj_on[r] = mask[b * N_ + jt * 64 + jsub + quad * 4 + r];

    __syncthreads();

    for (int kt = 0; kt < 32; ++kt) {
        const int cur = kt & 1, nxt = cur ^ 1;
        short8 rK[4];
        short4_t apn[2];
        int rmk = 0;
        if (kt < 31) {
            const size_t Kb2 = ((size_t)bh * N_ + (size_t)(kt + 1) * 64) * DH_;
#pragma unroll
            for (int i = 0; i < 4; ++i) {
                int c = tid + i * 512;
                int row = c >> 5, half = (c >> 4) & 1, seg = c & 15;
                rK[i] = *(const short8*)((half ? Klo : Khi) + Kb2 + (size_t)row * DH_ + seg * 8);
            }
#pragma unroll
            for (int nk = 0; nk < 2; ++nk)
                apn[nk] = *(const short4_t*)(ap_base + (size_t)((kt + 1) * 64 + nk * 16) * N_);
            if (tid < 64) rmk = mask[b * N_ + (kt + 1) * 64 + tid];
        }

        // MFMA: S[16 j][32 k per wave], kc-major, K-hi frags reused for t0/t2
        float4_t acc[2];
        acc[0] = (float4_t)(0.f); acc[1] = (float4_t)(0.f);
#pragma unroll
        for (int kc = 0; kc < 4; ++kc) {
            short8 bH[2], bL[2];
#pragma unroll
            for (int nk = 0; nk < 2; ++nk)
                bH[nk] = *(const short8*)(ldsK[cur] + (khalf * 32 + nk * 16 + l16) * 264 + kc * 32 + quad * 8);
#pragma unroll
            for (int nk = 0; nk < 2; ++nk)
                acc[nk] = __builtin_amdgcn_mfma_f32_16x16x32_bf16(rQh[kc], bH[nk], acc[nk], 0, 0, 0);
#pragma unroll
            for (int nk = 0; nk < 2; ++nk)
                acc[nk] = __builtin_amdgcn_mfma_f32_16x16x32_bf16(rQl[kc], bH[nk], acc[nk], 0, 0, 0);
#pragma unroll
            for (int nk = 0; nk < 2; ++nk)
                bL[nk] = *(const short8*)(ldsK[cur] + (khalf * 32 + nk * 16 + l16) * 264 + 128 + kc * 32 + quad * 8);
#pragma unroll
            for (int nk = 0; nk < 2; ++nk)
                acc[nk] = __builtin_amdgcn_mfma_f32_16x16x32_bf16(rQh[kc], bL[nk], acc[nk], 0, 0, 0);
        }

#pragma unroll
        for (int nk = 0; nk < 2; ++nk) {
            int kk = khalf * 32 + nk * 16 + l16;
            int mk = s_mk[cur][kk];
#pragma unroll
            for (int r = 0; r < 4; ++r) {
                float e = acc[nk][r] + bf2f((u16)apc[nk][r]);
                e = (mj_on[r] && mk) ? e : -1.0e9f;
                p[r] += __expf(e);
            }
        }

        if (kt < 31) {
#pragma unroll
            for (int i = 0; i < 4; ++i) {
                int c = tid + i * 512;
                int row = c >> 5, half = (c >> 4) & 1, seg = c & 15;
                *(short8*)(ldsK[nxt] + row * 264 + half * 128 + seg * 8) = rK[i];
            }
            if (tid < 64) s_mk[nxt][tid] = rmk;
            apc[0] = apn[0]; apc[1] = apn[1];
        }
        __syncthreads();
    }

    // reduce over l16 lanes, then over the two k-half waves
#pragma unroll
    for (int r = 0; r < 4; ++r) {
        float s = p[r];
        for (int off = 1; off < 16; off <<= 1)
            s += __shfl_xor(s, off, 64);
        if (l16 == 0)
            psum[(jsub + quad * 4 + r) * 2 + khalf] = s;
    }
    __syncthreads();
    if (tid < 64)
        lrow[(size_t)bh * N_ + jt * 64 + tid] = psum[tid * 2] + psum[tid * 2 + 1];
}

// ---------------------------------------------------------------------------
// Kernel 6 (pass B): y[i,e] = sum_j A[j,i] V[j,e], A = exp(E)/l_j.
// 512 thr / 8 waves.  K frags in registers.  AP loaded PER-LANE FROM GLOBAL
// (8B x2, 1-iter reg prefetch) -> ldsAPt deleted -> LDS 65.3 KB ->
// 2 blocks/CU resident (grid y-dim gives exactly 2 blocks per CU).
// ---------------------------------------------------------------------------
__global__ __launch_bounds__(512, 4) void attn_kernel(
    const u16* __restrict__ Qhi, const u16* __restrict__ Qlo,
    const u16* __restrict__ Khi, const u16* __restrict__ Klo,
    const u16* __restrict__ VT,
    const u16* __restrict__ APt,
    const int* __restrict__ mask,
    const float* __restrict__ lrow,
    u16* __restrict__ yout,               // [BS,N,D] bf16 (ws)
    float* __restrict__ aout)             // [BS,N,N] fp32 (d_out tail)
{
    const int it = blockIdx.x;   // 16 i-tiles (keys)
    const int bh = blockIdx.y;   // 32
    const int b = bh >> 3, h = bh & 7;
    const int tid = threadIdx.x, wave = tid >> 6, lane = tid & 63;  // 8 waves
    const int quad = lane >> 4, l16 = lane & 15;

    __shared__ __align__(16) u16 ldsQ[2][32 * 264];    // Q_j split, dbuf     (33.8 KB)
    __shared__ __align__(16) u16 ldsV[2][128 * 40];    // V^T [e][j], dbuf    (20.5 KB)
    __shared__ __align__(16) u16 ldsA[128 * 40];       // A^T [i][j]          (10.2 KB)
    __shared__ float s_il[2][32];
    __shared__ int   s_dead[2][32];
    __shared__ int   s_mj[2][32];

    const int i_local = wave * 16 + l16;
    const int ig = it * 128 + i_local;

    // K fragments resident in registers (8 x short8 = 32 VGPR)
    short8 rKh[4], rKl[4];
    {
        const size_t krow = ((size_t)bh * N_ + ig) * DH_;
#pragma unroll
        for (int kc = 0; kc < 4; ++kc) {
            rKh[kc] = *(const short8*)(Khi + krow + kc * 32 + quad * 8);
            rKl[kc] = *(const short8*)(Klo + krow + kc * 32 + quad * 8);
        }
    }

    // per-lane AP base: row = ig (fixed), col walks with jt
    const u16* ap_base = APt + (size_t)ig * N_ + quad * 4;
    short4_t apc[2];
#pragma unroll
    for (int mj = 0; mj < 2; ++mj)
        apc[mj] = *(const short4_t*)(ap_base + mj * 16);

    // buf0 (jt = 0)
    {
        const size_t Qb0 = ((size_t)bh * N_) * DH_;
        for (int c = tid; c < 1024; c += 512) {
            int row = c >> 5, half = (c >> 4) & 1, seg = c & 15;
            *(short8*)(ldsQ[0] + row * 264 + half * 128 + seg * 8) =
                *(const short8*)((half ? Qlo : Qhi) + Qb0 + (size_t)row * DH_ + seg * 8);
        }
        { int e = tid >> 2, seg = tid & 3;
          *(short8*)(ldsV[0] + e * 40 + seg * 8) =
              *(const short8*)(VT + (size_t)bh * DH_ * N_ + (size_t)e * N_ + seg * 8); }
        if (tid < 32) {
            float l = lrow[(size_t)bh * N_ + tid];
            int mj = mask[b * N_ + tid];
            int alive = (mj != 0) && (l > 0.f);
            s_il[0][tid] = alive ? 1.0f / l : 0.f;
            s_dead[0][tid] = !alive;
            s_mj[0][tid] = mj;
        }
    }

    const int ion = mask[b * N_ + ig];
    const int ip = wave >> 1, eh = wave & 1;   // MFMA2 retile: 4 i-pods x 2 e-halves

    float4_t accy[2][4];   // [ni][ne]: i = ip*32+ni*16.., e = eh*64+ne*16..
#pragma unroll
    for (int ni = 0; ni < 2; ++ni)
#pragma unroll
        for (int ne = 0; ne < 4; ++ne) accy[ni][ne] = (float4_t)(0.f);

    const bool do_aout = (h == 7);
    const float inv_n = 1.0f / (float)N_;

    __syncthreads();

    for (int jt = 0; jt < 64; ++jt) {
        const int cur = jt & 1, nxt = cur ^ 1;
        const int j0 = jt * 32;

        // prefetch next j-tile into registers (hidden under MFMA1+epi+MFMA2)
        short8 rQ[2], rV;
        short4_t apn[2];
        float r_il = 0.f; int r_dead = 0, r_mj = 0;
        if (jt < 63) {
            const int j0n = j0 + 32;
            const size_t Qb2 = ((size_t)bh * N_ + j0n) * DH_;
#pragma unroll
            for (int i = 0; i < 2; ++i) {
                int c = tid + i * 512;
                int row = c >> 5, half = (c >> 4) & 1, seg = c & 15;
                rQ[i] = *(const short8*)((half ? Qlo : Qhi) + Qb2 + (size_t)row * DH_ + seg * 8);
            }
            { int e = tid >> 2, seg = tid & 3;
              rV = *(const short8*)(VT + (size_t)bh * DH_ * N_ + (size_t)e * N_ + j0n + seg * 8); }
#pragma unroll
            for (int mj = 0; mj < 2; ++mj)
                apn[mj] = *(const short4_t*)(ap_base + j0n + mj * 16);
            if (tid < 32) {
                float l = lrow[(size_t)bh * N_ + j0n + tid];
                r_mj = mask[b * N_ + j0n + tid];
                int alive = (r_mj != 0) && (l > 0.f);
                r_il = alive ? 1.0f / l : 0.f;
                r_dead = !alive;
            }
        }

        // MFMA1: S[j(32), i(16 per wave)] — kc-major, per-acc order
        // (Qhi*Khi, Qlo*Khi, Qhi*Klo) bitwise-matches rowstats
        float4_t accs[2];
        accs[0] = (float4_t)(0.f); accs[1] = (float4_t)(0.f);
#pragma unroll
        for (int kc = 0; kc < 4; ++kc) {
            short8 aH[2], aL[2];
#pragma unroll
            for (int mj = 0; mj < 2; ++mj)
                aH[mj] = *(const short8*)(ldsQ[cur] + (mj * 16 + l16) * 264 + kc * 32 + quad * 8);
#pragma unroll
            for (int mj = 0; mj < 2; ++mj)
                accs[mj] = __builtin_amdgcn_mfma_f32_16x16x32_bf16(aH[mj], rKh[kc], accs[mj], 0, 0, 0);
#pragma unroll
            for (int mj = 0; mj < 2; ++mj)
                aL[mj] = *(const short8*)(ldsQ[cur] + (mj * 16 + l16) * 264 + 128 + kc * 32 + quad * 8);
#pragma unroll
            for (int mj = 0; mj < 2; ++mj)
                accs[mj] = __builtin_amdgcn_mfma_f32_16x16x32_bf16(aL[mj], rKh[kc], accs[mj], 0, 0, 0);
#pragma unroll
            for (int mj = 0; mj < 2; ++mj)
                accs[mj] = __builtin_amdgcn_mfma_f32_16x16x32_bf16(aH[mj], rKl[kc], accs[mj], 0, 0, 0);
        }

        // A = exp(E)*il (dead row -> 1/N); write A^T to LDS; h==7: fp32 out
#pragma unroll
        for (int mj = 0; mj < 2; ++mj) {
            short4_t pk;
#pragma unroll
            for (int r = 0; r < 4; ++r) {
                int jl = mj * 16 + quad * 4 + r;
                float e = accs[mj][r] + bf2f((u16)apc[mj][r]);
                e = (s_mj[cur][jl] && ion) ? e : -1.0e9f;
                float a = s_dead[cur][jl] ? inv_n : __expf(e) * s_il[cur][jl];
                pk[r] = (short)f2bf(a);
                if (do_aout)
                    aout[((size_t)(b * N_ + j0 + jl)) * N_ + ig] = a;
            }
            *(short4_t*)(ldsA + (size_t)i_local * 40 + mj * 16 + quad * 4) = pk;
        }
        __syncthreads();   // B1: ldsA ready; reads of ldsQ[cur] done

        // MFMA2: y[i(32 per pod), e(64 per half)] += A^T · V   (k = 32)
        {
            short8 afrA[2];
#pragma unroll
            for (int ni = 0; ni < 2; ++ni)
                afrA[ni] = *(const short8*)(ldsA + (ip * 32 + ni * 16 + l16) * 40 + quad * 8);
#pragma unroll
            for (int ne = 0; ne < 4; ++ne) {
                short8 bfr = *(const short8*)(ldsV[cur] + (eh * 64 + ne * 16 + l16) * 40 + quad * 8);
#pragma unroll
                for (int ni = 0; ni < 2; ++ni)
                    accy[ni][ne] = __builtin_amdgcn_mfma_f32_16x16x32_bf16(afrA[ni], bfr, accy[ni][ne], 0, 0, 0);
            }
        }

        if (jt < 63) {
#pragma unroll
            for (int i = 0; i < 2; ++i) {
                int c = tid + i * 512;
                int row = c >> 5, half = (c >> 4) & 1, seg = c & 15;
                *(short8*)(ldsQ[nxt] + row * 264 + half * 128 + seg * 8) = rQ[i];
            }
            { int e = tid >> 2, seg = tid & 3;
              *(short8*)(ldsV[nxt] + e * 40 + seg * 8) = rV; }
            if (tid < 32) {
                s_il[nxt][tid] = r_il;
                s_dead[nxt][tid] = r_dead;
                s_mj[nxt][tid] = r_mj;
            }
            apc[0] = apn[0]; apc[1] = apn[1];
        }
        __syncthreads();   // B2: buf[nxt] ready; ldsA reads done
    }

#pragma unroll
    for (int ni = 0; ni < 2; ++ni)
#pragma unroll
        for (int ne = 0; ne < 4; ++ne)
#pragma unroll
            for (int r = 0; r < 4; ++r) {
                int irow = ip * 32 + ni * 16 + quad * 4 + r;
                int e = eh * 64 + ne * 16 + l16;
                yout[((size_t)b * N_ + it * 128 + irow) * D_ + h * DH_ + e] =
                    f2bf(accy[ni][ne][r]);
            }
}

// ---------------------------------------------------------------------------
// Kernel 7: out[m,o] = sum_d y[m,d] Wout[o,d]  (unchanged).
// ---------------------------------------------------------------------------
__global__ __launch_bounds__(256, 4) void outgemm_kernel(
    const u16* __restrict__ A,     // y   [8192][1024] bf16
    const u16* __restrict__ B,     // Wout[1024][1024] bf16 (hi)
    float* __restrict__ C)         // out [8192][1024] fp32
{
    const int nt = blockIdx.x;   // 8
    const int mt = blockIdx.y;   // 64
    const int tid = threadIdx.x, wave = tid >> 6, lane = tid & 63;
    const int quad = lane >> 4, l16 = lane & 15;

    __shared__ __align__(16) u16 sA[128 * 32];
    __shared__ __align__(16) u16 sB[128 * 32];

    const int srow = lane >> 2, scol = (lane & 3) * 8;
    const size_t aoff = ((size_t)(mt * 128) + srow) * 1024 + scol;
    const size_t boff = ((size_t)(nt * 128) + srow) * 1024 + scol;
    const int r0 = wave * 16, r1 = 64 + wave * 16;

    float4_t acc[2][8];
#pragma unroll
    for (int i = 0; i < 2; ++i)
#pragma unroll
        for (int j = 0; j < 8; ++j) acc[i][j] = (float4_t)(0.f);

    for (int kt = 0; kt < 32; ++kt) {
        __syncthreads();
        const int kc0 = kt * 32;
        gl_lds16(A + aoff + (size_t)r0 * 1024 + kc0, &sA[r0 * 32]);
        gl_lds16(A + aoff + (size_t)r1 * 1024 + kc0, &sA[r1 * 32]);
        gl_lds16(B + boff + (size_t)r0 * 1024 + kc0, &sB[r0 * 32]);
        gl_lds16(B + boff + (size_t)r1 * 1024 + kc0, &sB[r1 * 32]);
        __syncthreads();

        short8 afr[2];
#pragma unroll
        for (int mi = 0; mi < 2; ++mi)
            afr[mi] = *(const short8*)(sA + (wave * 32 + mi * 16 + l16) * 32 + quad * 8);
#pragma unroll
        for (int ne = 0; ne < 8; ++ne) {
            short8 bfr = *(const short8*)(sB + (ne * 16 + l16) * 32 + quad * 8);
#pragma unroll
            for (int mi = 0; mi < 2; ++mi)
                acc[mi][ne] = __builtin_amdgcn_mfma_f32_16x16x32_bf16(afr[mi], bfr, acc[mi][ne], 0, 0, 0);
        }
    }

#pragma unroll
    for (int mi = 0; mi < 2; ++mi)
#pragma unroll
        for (int ne = 0; ne < 8; ++ne)
#pragma unroll
            for (int r = 0; r < 4; ++r) {
                int row = mt * 128 + wave * 32 + mi * 16 + quad * 4 + r;
                int col = nt * 128 + ne * 16 + l16;
                C[(size_t)row * D_ + col] = acc[mi][ne][r];
            }
}

// ---------------------------------------------------------------------------
extern "C" void kernel_launch(void* const* d_in, const int* in_sizes, int n_in,
                              void* d_out, int out_size, void* d_ws, size_t ws_size,
                              hipStream_t stream)
{
    const float* x   = (const float*)d_in[0];
    const int*   msk = (const int*)d_in[1];
    const float* Wq  = (const float*)d_in[2];
    const float* Wk  = (const float*)d_in[3];
    const float* Wv  = (const float*)d_in[4];
    const float* Wo  = (const float*)d_in[5];

    float* out  = (float*)d_out;                         // [4,2048,1024] fp32
    float* aout = out + (size_t)BS_ * N_ * D_;           // [4,2048,2048] fp32

    // transient split buffers in d_out (dead before attn/outgemm overwrite)
    u16* Whi  = (u16*)d_out;                       // 2048*1024
    u16* Wlo  = Whi  + (size_t)2048 * 1024;        // 2048*1024
    u16* Wvhi = Wlo  + (size_t)2048 * 1024;        // 1024*1024
    u16* Xhi  = Wvhi + (size_t)1024 * 1024;        // 8192*1024
    u16* Xlo  = Xhi  + (size_t)8192 * 1024;        // 8192*1024

    // workspace (111.4 MB)
    char* w = (char*)d_ws;
    u16* APt = (u16*)w;                       w += (size_t)N_ * N_ * 2;   // transposed AP
    const size_t szqk = (size_t)BS_ * H_ * N_ * DH_ * 2;
    u16* Qhi = (u16*)w; w += szqk;
    u16* Qlo = (u16*)w; w += szqk;
    u16* Khi = (u16*)w; w += szqk;
    u16* Klo = (u16*)w; w += szqk;
    u16* VT  = (u16*)w; w += szqk;
    float* lrow = (float*)w;                  w += (size_t)BS_ * H_ * N_ * 4;
    u16* Wohi = (u16*)w;                      w += (size_t)D_ * D_ * 2;
    u16* yb   = (u16*)w;                      w += (size_t)BS_ * N_ * D_ * 2;

    apt_kernel<<<8192, 256, 0, stream>>>((unsigned int*)APt);
    split_kernel<<<12288, 256, 0, stream>>>(x, Wq, Wk, Wv, Wo,
                                            Xhi, Xlo, Whi, Wlo, Wvhi, Wohi);
    qk_gemm<<<dim3(64, 16), 256, 0, stream>>>(Xhi, Xlo, Whi, Wlo,
                                              Qhi, Qlo, Khi, Klo);
    v_gemm<<<dim3(16, 32), 256, 0, stream>>>(Wvhi, Xhi, VT);
    rowstats_kernel<<<dim3(32, 32), 512, 0, stream>>>(Qhi, Qlo, Khi, Klo, APt, msk, lrow);
    attn_kernel<<<dim3(16, 32), 512, 0, stream>>>(Qhi, Qlo, Khi, Klo, VT, APt, msk,
                                                  lrow, yb, aout);
    outgemm_kernel<<<dim3(8, 64), 256, 0, stream>>>(yb, Wohi, out);
}

// Round 3
// 673.601 us; speedup vs baseline: 1.2225x; 1.0141x over previous
//
#include <hip/hip_runtime.h>
#include <math.h>

// Problem constants
#define BS_ 4
#define N_  2048
#define D_  1024
#define H_  8
#define DH_ 128

typedef __attribute__((ext_vector_type(8))) short short8;
typedef __attribute__((ext_vector_type(4))) short short4_t;
typedef __attribute__((ext_vector_type(4))) float float4_t;
typedef unsigned short u16;

__device__ __forceinline__ u16 f2bf(float f) {
    union { float f; unsigned u; } v; v.f = f;
    unsigned r = v.u + 0x7FFFu + ((v.u >> 16) & 1u);   // RNE
    return (u16)(r >> 16);
}
__device__ __forceinline__ float bf2f(u16 h) {
    union { unsigned u; float f; } v; v.u = ((unsigned)h) << 16;
    return v.f;
}
__device__ __forceinline__ void split4(float a, float b, float c, float d,
                                       short4_t* hi, short4_t* lo) {
    u16 h0 = f2bf(a), h1 = f2bf(b), h2 = f2bf(c), h3 = f2bf(d);
    (*hi)[0] = (short)h0; (*hi)[1] = (short)h1; (*hi)[2] = (short)h2; (*hi)[3] = (short)h3;
    (*lo)[0] = (short)f2bf(a - bf2f(h0));
    (*lo)[1] = (short)f2bf(b - bf2f(h1));
    (*lo)[2] = (short)f2bf(c - bf2f(h2));
    (*lo)[3] = (short)f2bf(d - bf2f(h3));
}

// async global->LDS, 16B per lane; LDS dest = wave-uniform base + lane*16.
__device__ __forceinline__ void gl_lds16(const void* g, void* l) {
    __builtin_amdgcn_global_load_lds(
        (const __attribute__((address_space(1))) unsigned int*)g,
        (__attribute__((address_space(3))) unsigned int*)l,
        16, 0, 0);
}

// ---------------------------------------------------------------------------
// Kernel 1: TRANSPOSED AP table, bf16.  APt[i][j] = AP[j][i]:
//   i even: sin(j * w_u), i odd: cos(j * w_u), u = i>>1, w_u = 10000^(-u/512).
// ---------------------------------------------------------------------------
__global__ void apt_kernel(unsigned int* __restrict__ APtw) {
    int idx = blockIdx.x * 256 + threadIdx.x;   // 2,097,152 = 2048 rows * 1024 words
    int i = idx >> 10;             // row (feature index) 0..2047
    int jw = idx & 1023;           // word within row; j0 = 2*jw
    int u = i >> 1;
    float ex = exp2f(-(float)u * (13.287712379549449f / 512.0f));
    float a0 = (float)(2 * jw) * ex;
    float a1 = (float)(2 * jw + 1) * ex;
    float v0, v1;
    if (i & 1) { v0 = cosf(a0); v1 = cosf(a1); }
    else       { v0 = sinf(a0); v1 = sinf(a1); }
    APtw[(size_t)i * (N_ / 2) + jw] = (unsigned)f2bf(v0) | ((unsigned)f2bf(v1) << 16);
}

// ---------------------------------------------------------------------------
// Kernel 2: fp32 -> bf16 hi/lo pre-split of X, Wq|Wk (cat), Wv (hi), Wout (hi).
// ---------------------------------------------------------------------------
__global__ void split_kernel(const float* __restrict__ x,
                             const float* __restrict__ Wq, const float* __restrict__ Wk,
                             const float* __restrict__ Wv, const float* __restrict__ Wo,
                             u16* __restrict__ Xhi, u16* __restrict__ Xlo,
                             u16* __restrict__ Whi, u16* __restrict__ Wlo,
                             u16* __restrict__ Wvhi, u16* __restrict__ Wohi) {
    int i = blockIdx.x * 256 + threadIdx.x;            // 3,145,728 float4s
    const float* src; u16 *dhi, *dlo; size_t off;
    if (i < 2097152)      { src = x  + 4*(size_t)i;             dhi = Xhi;  dlo = Xlo;  off = 4*(size_t)i; }
    else if (i < 2359296) { size_t j = i - 2097152; src = Wq + 4*j; dhi = Whi; dlo = Wlo; off = 4*j; }
    else if (i < 2621440) { size_t j = i - 2359296; src = Wk + 4*j; dhi = Whi; dlo = Wlo; off = 1048576 + 4*j; }
    else if (i < 2883584) { size_t j = i - 2621440; src = Wv + 4*j; dhi = Wvhi; dlo = nullptr; off = 4*j; }
    else                  { size_t j = i - 2883584; src = Wo + 4*j; dhi = Wohi; dlo = nullptr; off = 4*j; }
    float4 v = *(const float4*)src;
    short4_t hi, lo;
    split4(v.x, v.y, v.z, v.w, &hi, &lo);
    *(short4_t*)(dhi + off) = hi;
    if (dlo) *(short4_t*)(dlo + off) = lo;
}

// ---------------------------------------------------------------------------
// Kernel 3: Q,K projections.  3-term bf16 split, m97 structure (unchanged).
// ---------------------------------------------------------------------------
__global__ __launch_bounds__(256, 4) void qk_gemm(
    const u16* __restrict__ Xhi, const u16* __restrict__ Xlo,
    const u16* __restrict__ Whi, const u16* __restrict__ Wlo,
    u16* __restrict__ Qhi, u16* __restrict__ Qlo,
    u16* __restrict__ Khi, u16* __restrict__ Klo)
{
    const int mt = blockIdx.x;   // 64
    const int nt = blockIdx.y;   // 16
    const int tid = threadIdx.x, wave = tid >> 6, lane = tid & 63;
    const int quad = lane >> 4, l16 = lane & 15;

    __shared__ __align__(16) u16 sA[2][128 * 32];
    __shared__ __align__(16) u16 sB[2][128 * 32];

    const int srow = lane >> 2;
    const int scol = (lane & 3) * 8;
    const size_t aoff = ((size_t)(mt * 128) + srow) * 1024 + scol;
    const size_t boff = ((size_t)(nt * 128) + srow) * 1024 + scol;
    const int r0 = wave * 16, r1 = 64 + wave * 16;

    float4_t acc[2][8];
#pragma unroll
    for (int i = 0; i < 2; ++i)
#pragma unroll
        for (int j = 0; j < 8; ++j) acc[i][j] = (float4_t)(0.f);

    for (int kt = 0; kt < 32; ++kt) {
        __syncthreads();
        const int kc0 = kt * 32;
        gl_lds16(Xhi + aoff + (size_t)r0 * 1024 + kc0, &sA[0][r0 * 32]);
        gl_lds16(Xhi + aoff + (size_t)r1 * 1024 + kc0, &sA[0][r1 * 32]);
        gl_lds16(Xlo + aoff + (size_t)r0 * 1024 + kc0, &sA[1][r0 * 32]);
        gl_lds16(Xlo + aoff + (size_t)r1 * 1024 + kc0, &sA[1][r1 * 32]);
        gl_lds16(Whi + boff + (size_t)r0 * 1024 + kc0, &sB[0][r0 * 32]);
        gl_lds16(Whi + boff + (size_t)r1 * 1024 + kc0, &sB[0][r1 * 32]);
        gl_lds16(Wlo + boff + (size_t)r0 * 1024 + kc0, &sB[1][r0 * 32]);
        gl_lds16(Wlo + boff + (size_t)r1 * 1024 + kc0, &sB[1][r1 * 32]);
        __syncthreads();

#pragma unroll
        for (int t = 0; t < 3; ++t) {
            const u16* As = sA[t == 2 ? 1 : 0];
            const u16* Bs = sB[t == 1 ? 1 : 0];
            short8 afr[2];
#pragma unroll
            for (int mi = 0; mi < 2; ++mi)
                afr[mi] = *(const short8*)(As + (wave * 32 + mi * 16 + l16) * 32 + quad * 8);
#pragma unroll
            for (int ne = 0; ne < 8; ++ne) {
                short8 bfr = *(const short8*)(Bs + (ne * 16 + l16) * 32 + quad * 8);
#pragma unroll
                for (int mi = 0; mi < 2; ++mi)
                    acc[mi][ne] = __builtin_amdgcn_mfma_f32_16x16x32_bf16(afr[mi], bfr, acc[mi][ne], 0, 0, 0);
            }
        }
    }

    const int b = mt >> 4, q0 = (mt & 15) * 128;
    const bool isQ = (nt < 8);
    u16* Hi = isQ ? Qhi : Khi;
    u16* Lo = isQ ? Qlo : Klo;
    const int h = isQ ? nt : nt - 8;
    const size_t base = (size_t)(b * 8 + h) * N_ * DH_;
#pragma unroll
    for (int mi = 0; mi < 2; ++mi)
#pragma unroll
        for (int ne = 0; ne < 8; ++ne)
#pragma unroll
            for (int r = 0; r < 4; ++r) {
                int q = q0 + wave * 32 + mi * 16 + quad * 4 + r;
                int e = ne * 16 + l16;
                float v = acc[mi][ne][r];
                u16 hv = f2bf(v);
                Hi[base + (size_t)q * DH_ + e] = hv;
                Lo[base + (size_t)q * DH_ + e] = f2bf(v - bf2f(hv));
            }
}

// ---------------------------------------------------------------------------
// Kernel 4: V^T[bh][e][q]  (1-term bf16, unchanged).
// ---------------------------------------------------------------------------
__global__ __launch_bounds__(256, 4) void v_gemm(
    const u16* __restrict__ Wvhi, const u16* __restrict__ Xhi,
    u16* __restrict__ VT)
{
    const int qt = blockIdx.x;   // 16
    const int bh = blockIdx.y;   // 32
    const int b = bh >> 3, h = bh & 7;
    const int tid = threadIdx.x, wave = tid >> 6, lane = tid & 63;
    const int quad = lane >> 4, l16 = lane & 15;

    __shared__ __align__(16) u16 sA[128 * 32];
    __shared__ __align__(16) u16 sB[128 * 32];

    const int srow = lane >> 2, scol = (lane & 3) * 8;
    const size_t aoff = ((size_t)(h * 128) + srow) * 1024 + scol;
    const size_t boff = ((size_t)(b * N_ + qt * 128) + srow) * 1024 + scol;
    const int r0 = wave * 16, r1 = 64 + wave * 16;

    float4_t acc[2][8];
#pragma unroll
    for (int i = 0; i < 2; ++i)
#pragma unroll
        for (int j = 0; j < 8; ++j) acc[i][j] = (float4_t)(0.f);

    for (int kt = 0; kt < 32; ++kt) {
        __syncthreads();
        const int kc0 = kt * 32;
        gl_lds16(Wvhi + aoff + (size_t)r0 * 1024 + kc0, &sA[r0 * 32]);
        gl_lds16(Wvhi + aoff + (size_t)r1 * 1024 + kc0, &sA[r1 * 32]);
        gl_lds16(Xhi  + boff + (size_t)r0 * 1024 + kc0, &sB[r0 * 32]);
        gl_lds16(Xhi  + boff + (size_t)r1 * 1024 + kc0, &sB[r1 * 32]);
        __syncthreads();

        short8 afr[2];
#pragma unroll
        for (int mi = 0; mi < 2; ++mi)
            afr[mi] = *(const short8*)(sA + (wave * 32 + mi * 16 + l16) * 32 + quad * 8);
#pragma unroll
        for (int ne = 0; ne < 8; ++ne) {
            short8 bfr = *(const short8*)(sB + (ne * 16 + l16) * 32 + quad * 8);
#pragma unroll
            for (int mi = 0; mi < 2; ++mi)
                acc[mi][ne] = __builtin_amdgcn_mfma_f32_16x16x32_bf16(afr[mi], bfr, acc[mi][ne], 0, 0, 0);
        }
    }

    u16* Cg = VT + (size_t)bh * DH_ * N_;
#pragma unroll
    for (int mi = 0; mi < 2; ++mi)
#pragma unroll
        for (int ne = 0; ne < 8; ++ne)
#pragma unroll
            for (int r = 0; r < 4; ++r) {
                int e = wave * 32 + mi * 16 + quad * 4 + r;
                int q = qt * 128 + ne * 16 + l16;
                Cg[(size_t)e * N_ + q] = f2bf(acc[mi][ne][r]);
            }
}

// ---------------------------------------------------------------------------
// Kernel 5 (pass A): l_j = sum_k exp(E[j,k]).  512 thr / 8 waves (unchanged).
// ---------------------------------------------------------------------------
__global__ __launch_bounds__(512, 4) void rowstats_kernel(
    const u16* __restrict__ Qhi, const u16* __restrict__ Qlo,
    const u16* __restrict__ Khi, const u16* __restrict__ Klo,
    const u16* __restrict__ APt,
    const int* __restrict__ mask,
    float* __restrict__ lrow)
{
    const int jt = blockIdx.x;    // 32 j-tiles of 64
    const int bh = blockIdx.y;    // 32
    const int b = bh >> 3;
    const int tid = threadIdx.x, wave = tid >> 6, lane = tid & 63;
    const int quad = lane >> 4, l16 = lane & 15;
    const int jsub = (wave & 3) * 16, khalf = wave >> 2;

    __shared__ __align__(16) u16 ldsK[2][64 * 264];    // streamed, split (66 KB)
    __shared__ int   s_mk[2][64];
    __shared__ float psum[64 * 2];

    // Q fragments resident in registers (8 x short8 = 32 VGPR)
    short8 rQh[4], rQl[4];
    {
        const size_t qrow = ((size_t)bh * N_ + (size_t)(jt * 64 + jsub + l16)) * DH_;
#pragma unroll
        for (int kc = 0; kc < 4; ++kc) {
            rQh[kc] = *(const short8*)(Qhi + qrow + kc * 32 + quad * 8);
            rQl[kc] = *(const short8*)(Qlo + qrow + kc * 32 + quad * 8);
        }
    }

    // per-lane AP base: row = key index (khalf*32 + nk*16 + l16), col fixed
    const u16* ap_base = APt + (size_t)(khalf * 32 + l16) * N_ + jt * 64 + jsub + quad * 4;
    short4_t apc[2];
#pragma unroll
    for (int nk = 0; nk < 2; ++nk)
        apc[nk] = *(const short4_t*)(ap_base + (size_t)(nk * 16) * N_);

    // buf0: K tile 0 + mask
    {
        const size_t Kb = ((size_t)bh * N_) * DH_;
        for (int c = tid; c < 2048; c += 512) {
            int row = c >> 5, half = (c >> 4) & 1, seg = c & 15;
            *(short8*)(ldsK[0] + row * 264 + half * 128 + seg * 8) =
                *(const short8*)((half ? Klo : Khi) + Kb + (size_t)row * DH_ + seg * 8);
        }
        if (tid < 64) s_mk[0][tid] = mask[b * N_ + tid];
    }

    float p[4] = {0.f, 0.f, 0.f, 0.f};
    int mj_on[4];
#pragma unroll
    for (int r = 0; r < 4; ++r)
        mj_on[r] = mask[b * N_ + jt * 64 + jsub + quad * 4 + r];

    __syncthreads();

    for (int kt = 0; kt < 32; ++kt) {
        const int cur = kt & 1, nxt = cur ^ 1;
        short8 rK[4];
        short4_t apn[2];
        int rmk = 0;
        if (kt < 31) {
            const size_t Kb2 = ((size_t)bh * N_ + (size_t)(kt + 1) * 64) * DH_;
#pragma unroll
            for (int i = 0; i < 4; ++i) {
                int c = tid + i * 512;
                int row = c >> 5, half = (c >> 4) & 1, seg = c & 15;
                rK[i] = *(const short8*)((half ? Klo : Khi) + Kb2 + (size_t)row * DH_ + seg * 8);
            }
#pragma unroll
            for (int nk = 0; nk < 2; ++nk)
                apn[nk] = *(const short4_t*)(ap_base + (size_t)((kt + 1) * 64 + nk * 16) * N_);
            if (tid < 64) rmk = mask[b * N_ + (kt + 1) * 64 + tid];
        }

        // MFMA: S[16 j][32 k per wave], kc-major, K-hi frags reused for t0/t2
        float4_t acc[2];
        acc[0] = (float4_t)(0.f); acc[1] = (float4_t)(0.f);
#pragma unroll
        for (int kc = 0; kc < 4; ++kc) {
            short8 bH[2], bL[2];
#pragma unroll
            for (int nk = 0; nk < 2; ++nk)
                bH[nk] = *(const short8*)(ldsK[cur] + (khalf * 32 + nk * 16 + l16) * 264 + kc * 32 + quad * 8);
#pragma unroll
            for (int nk = 0; nk < 2; ++nk)
                acc[nk] = __builtin_amdgcn_mfma_f32_16x16x32_bf16(rQh[kc], bH[nk], acc[nk], 0, 0, 0);
#pragma unroll
            for (int nk = 0; nk < 2; ++nk)
                acc[nk] = __builtin_amdgcn_mfma_f32_16x16x32_bf16(rQl[kc], bH[nk], acc[nk], 0, 0, 0);
#pragma unroll
            for (int nk = 0; nk < 2; ++nk)
                bL[nk] = *(const short8*)(ldsK[cur] + (khalf * 32 + nk * 16 + l16) * 264 + 128 + kc * 32 + quad * 8);
#pragma unroll
            for (int nk = 0; nk < 2; ++nk)
                acc[nk] = __builtin_amdgcn_mfma_f32_16x16x32_bf16(rQh[kc], bL[nk], acc[nk], 0, 0, 0);
        }

#pragma unroll
        for (int nk = 0; nk < 2; ++nk) {
            int kk = khalf * 32 + nk * 16 + l16;
            int mk = s_mk[cur][kk];
#pragma unroll
            for (int r = 0; r < 4; ++r) {
                float e = acc[nk][r] + bf2f((u16)apc[nk][r]);
                e = (mj_on[r] && mk) ? e : -1.0e9f;
                p[r] += __expf(e);
            }
        }

        if (kt < 31) {
#pragma unroll
            for (int i = 0; i < 4; ++i) {
                int c = tid + i * 512;
                int row = c >> 5, half = (c >> 4) & 1, seg = c & 15;
                *(short8*)(ldsK[nxt] + row * 264 + half * 128 + seg * 8) = rK[i];
            }
            if (tid < 64) s_mk[nxt][tid] = rmk;
            apc[0] = apn[0]; apc[1] = apn[1];
        }
        __syncthreads();
    }

    // reduce over l16 lanes, then over the two k-half waves
#pragma unroll
    for (int r = 0; r < 4; ++r) {
        float s = p[r];
        for (int off = 1; off < 16; off <<= 1)
            s += __shfl_xor(s, off, 64);
        if (l16 == 0)
            psum[(jsub + quad * 4 + r) * 2 + khalf] = s;
    }
    __syncthreads();
    if (tid < 64)
        lrow[(size_t)bh * N_ + jt * 64 + tid] = psum[tid * 2] + psum[tid * 2 + 1];
}

// ---------------------------------------------------------------------------
// Kernel 6 (pass B): y[i,e] = sum_j A[j,i] V[j,e], A = exp(E)/l_j.
// 512 thr / 8 waves.  This round:
//  - MFMA1 wave remap: 4 i-quarters x 2 j-halves; each wave owns 32 i in regs
//    (K hi/lo 64 VGPR) and reads only its j-half's Q frags (LDS Q reads
//    128 -> 64 b128 per iter).  Per-acc product order (hi*Khi, lo*Khi,
//    hi*Klo) preserved -> E bitwise-matches rowstats.
//  - Fused g-table: one float per j (dead -> -1, else 1/l).  alive <=> mask_j
//    (mask_j=1 implies l >= exp(E[j,j]) > 0).  Replaces s_il/s_dead/s_mj and
//    their 24 ds_read_b32/lane with ONE broadcast ds_read_b128.
//  - V tile un-padded [e][32] (bank-balanced) staged via async
//    global_load_lds issued at iter top; removes reg round-trip + LDS writes.
// ---------------------------------------------------------------------------
__global__ __launch_bounds__(512, 3) void attn_kernel(
    const u16* __restrict__ Qhi, const u16* __restrict__ Qlo,
    const u16* __restrict__ Khi, const u16* __restrict__ Klo,
    const u16* __restrict__ VT,
    const u16* __restrict__ APt,
    const int* __restrict__ mask,
    const float* __restrict__ lrow,
    u16* __restrict__ yout,               // [BS,N,D] bf16 (ws)
    float* __restrict__ aout)             // [BS,N,N] fp32 (d_out tail)
{
    const int it = blockIdx.x;   // 16 i-tiles (keys)
    const int bh = blockIdx.y;   // 32
    const int b = bh >> 3, h = bh & 7;
    const int tid = threadIdx.x, wave = tid >> 6, lane = tid & 63;  // 8 waves
    const int quad = lane >> 4, l16 = lane & 15;

    __shared__ __align__(16) u16 ldsQ[2][32 * 264];    // Q_j split, dbuf     (33.8 KB)
    __shared__ __align__(16) u16 ldsV[2][128 * 32];    // V^T [e][j], dbuf    (16 KB, DMA)
    __shared__ __align__(16) u16 ldsA[128 * 40];       // A^T [i][j]          (10.2 KB)
    __shared__ __align__(16) float s_g[2][32];         // per-j: dead?-1:1/l

    // MFMA1 mapping: wave = iq (i-quarter) x jh (j-half)
    const int iq = wave & 3, jh = wave >> 2;
    const int igv0 = it * 128 + iq * 32 + l16;         // ih = 0
    const int igv1 = igv0 + 16;                        // ih = 1

    // K fragments resident in registers: 32 i rows/wave (16 x short8 = 64 VGPR)
    short8 rKh[4][2], rKl[4][2];
    {
        const size_t kr0 = ((size_t)bh * N_ + igv0) * DH_;
        const size_t kr1 = ((size_t)bh * N_ + igv1) * DH_;
#pragma unroll
        for (int kc = 0; kc < 4; ++kc) {
            rKh[kc][0] = *(const short8*)(Khi + kr0 + kc * 32 + quad * 8);
            rKh[kc][1] = *(const short8*)(Khi + kr1 + kc * 32 + quad * 8);
            rKl[kc][0] = *(const short8*)(Klo + kr0 + kc * 32 + quad * 8);
            rKl[kc][1] = *(const short8*)(Klo + kr1 + kc * 32 + quad * 8);
        }
    }

    // per-lane AP base: row = i (fixed per ih), col walks with jt
    const u16* apb0 = APt + (size_t)igv0 * N_ + jh * 16 + quad * 4;
    const u16* apb1 = APt + (size_t)igv1 * N_ + jh * 16 + quad * 4;
    short4_t apc[2];
    apc[0] = *(const short4_t*)(apb0);
    apc[1] = *(const short4_t*)(apb1);

    const int ion0 = mask[b * N_ + igv0];
    const int ion1 = mask[b * N_ + igv1];

    // buf0 (jt = 0)
    {
        const size_t Qb0 = ((size_t)bh * N_) * DH_;
        for (int c = tid; c < 1024; c += 512) {
            int row = c >> 5, half = (c >> 4) & 1, seg = c & 15;
            *(short8*)(ldsQ[0] + row * 264 + half * 128 + seg * 8) =
                *(const short8*)((half ? Qlo : Qhi) + Qb0 + (size_t)row * DH_ + seg * 8);
        }
        { int e = tid >> 2, seg = tid & 3;
          gl_lds16(VT + (size_t)bh * DH_ * N_ + (size_t)e * N_ + seg * 8,
                   &ldsV[0][wave * 512]); }
        if (tid < 32) {
            float l = lrow[(size_t)bh * N_ + tid];
            int mj = mask[b * N_ + tid];
            s_g[0][tid] = (mj && l > 0.f) ? 1.0f / l : -1.0f;
        }
    }

    const int ip = wave >> 1, eh = wave & 1;   // MFMA2 retile: 4 i-pods x 2 e-halves

    float4_t accy[2][4];   // [ni][ne]: i = ip*32+ni*16.., e = eh*64+ne*16..
#pragma unroll
    for (int ni = 0; ni < 2; ++ni)
#pragma unroll
        for (int ne = 0; ne < 4; ++ne) accy[ni][ne] = (float4_t)(0.f);

    const bool do_aout = (h == 7);
    const float inv_n = 1.0f / (float)N_;

    __syncthreads();

    for (int jt = 0; jt < 64; ++jt) {
        const int cur = jt & 1, nxt = cur ^ 1;
        const int j0 = jt * 32;

        // prefetch next j-tile (V via async DMA into ldsV[nxt]; Q/AP/g to regs)
        short8 rQ[2];
        short4_t apn[2];
        float r_g = 0.f;
        if (jt < 63) {
            const int j0n = j0 + 32;
            { int e = tid >> 2, seg = tid & 3;
              gl_lds16(VT + (size_t)bh * DH_ * N_ + (size_t)e * N_ + j0n + seg * 8,
                       &ldsV[nxt][wave * 512]); }
            const size_t Qb2 = ((size_t)bh * N_ + j0n) * DH_;
#pragma unroll
            for (int i = 0; i < 2; ++i) {
                int c = tid + i * 512;
                int row = c >> 5, half = (c >> 4) & 1, seg = c & 15;
                rQ[i] = *(const short8*)((half ? Qlo : Qhi) + Qb2 + (size_t)row * DH_ + seg * 8);
            }
            apn[0] = *(const short4_t*)(apb0 + j0n);
            apn[1] = *(const short4_t*)(apb1 + j0n);
            if (tid < 32) {
                float l = lrow[(size_t)bh * N_ + j0n + tid];
                int mj = mask[b * N_ + j0n + tid];
                r_g = (mj && l > 0.f) ? 1.0f / l : -1.0f;
            }
        }

        // MFMA1: S[j 16 (this wave's half)][i 32] — kc-major, per-acc order
        // (Qhi*Khi, Qlo*Khi, Qhi*Klo) bitwise-matches rowstats
        float4_t accs[2];   // [ih]
        accs[0] = (float4_t)(0.f); accs[1] = (float4_t)(0.f);
        const u16* qbase = ldsQ[cur] + (jh * 16 + l16) * 264 + quad * 8;
#pragma unroll
        for (int kc = 0; kc < 4; ++kc) {
            short8 aH = *(const short8*)(qbase + kc * 32);
            accs[0] = __builtin_amdgcn_mfma_f32_16x16x32_bf16(aH, rKh[kc][0], accs[0], 0, 0, 0);
            accs[1] = __builtin_amdgcn_mfma_f32_16x16x32_bf16(aH, rKh[kc][1], accs[1], 0, 0, 0);
            short8 aL = *(const short8*)(qbase + 128 + kc * 32);
            accs[0] = __builtin_amdgcn_mfma_f32_16x16x32_bf16(aL, rKh[kc][0], accs[0], 0, 0, 0);
            accs[1] = __builtin_amdgcn_mfma_f32_16x16x32_bf16(aL, rKh[kc][1], accs[1], 0, 0, 0);
            accs[0] = __builtin_amdgcn_mfma_f32_16x16x32_bf16(aH, rKl[kc][0], accs[0], 0, 0, 0);
            accs[1] = __builtin_amdgcn_mfma_f32_16x16x32_bf16(aH, rKl[kc][1], accs[1], 0, 0, 0);
        }

        // A = exp(E)*g (g<0 -> dead row -> 1/N); write A^T to LDS; h==7: fp32 out
        {
            float4_t g4 = *(const float4_t*)(&s_g[cur][jh * 16 + quad * 4]);
#pragma unroll
            for (int ih = 0; ih < 2; ++ih) {
                const int ig = ih ? igv1 : igv0;
                const int ion = ih ? ion1 : ion0;
                short4_t pk;
#pragma unroll
                for (int r = 0; r < 4; ++r) {
                    int jl = jh * 16 + quad * 4 + r;
                    float e = accs[ih][r] + bf2f((u16)apc[ih][r]);
                    float g = g4[r];
                    float a = (g < 0.f) ? inv_n : (ion ? __expf(e) * g : 0.f);
                    pk[r] = (short)f2bf(a);
                    if (do_aout)
                        aout[((size_t)(b * N_ + j0 + jl)) * N_ + ig] = a;
                }
                *(short4_t*)(ldsA + (size_t)(iq * 32 + ih * 16 + l16) * 40 + jh * 16 + quad * 4) = pk;
            }
        }
        __syncthreads();   // B1: ldsA ready; reads of ldsQ[cur] done

        // MFMA2: y[i(32 per pod), e(64 per half)] += A^T · V   (k = 32)
        {
            short8 afrA[2];
#pragma unroll
            for (int ni = 0; ni < 2; ++ni)
                afrA[ni] = *(const short8*)(ldsA + (ip * 32 + ni * 16 + l16) * 40 + quad * 8);
#pragma unroll
            for (int ne = 0; ne < 4; ++ne) {
                short8 bfr = *(const short8*)(ldsV[cur] + (eh * 64 + ne * 16 + l16) * 32 + quad * 8);
#pragma unroll
                for (int ni = 0; ni < 2; ++ni)
                    accy[ni][ne] = __builtin_amdgcn_mfma_f32_16x16x32_bf16(afrA[ni], bfr, accy[ni][ne], 0, 0, 0);
            }
        }

        if (jt < 63) {
#pragma unroll
            for (int i = 0; i < 2; ++i) {
                int c = tid + i * 512;
                int row = c >> 5, half = (c >> 4) & 1, seg = c & 15;
                *(short8*)(ldsQ[nxt] + row * 264 + half * 128 + seg * 8) = rQ[i];
            }
            if (tid < 32) s_g[nxt][tid] = r_g;
            apc[0] = apn[0]; apc[1] = apn[1];
        }
        __syncthreads();   // B2: buf[nxt] ready (incl. V DMA drain); ldsA reads done
    }

#pragma unroll
    for (int ni = 0; ni < 2; ++ni)
#pragma unroll
        for (int ne = 0; ne < 4; ++ne)
#pragma unroll
            for (int r = 0; r < 4; ++r) {
                int irow = ip * 32 + ni * 16 + quad * 4 + r;
                int e = eh * 64 + ne * 16 + l16;
                yout[((size_t)b * N_ + it * 128 + irow) * D_ + h * DH_ + e] =
                    f2bf(accy[ni][ne][r]);
            }
}

// ---------------------------------------------------------------------------
// Kernel 7: out[m,o] = sum_d y[m,d] Wout[o,d]  (unchanged).
// ---------------------------------------------------------------------------
__global__ __launch_bounds__(256, 4) void outgemm_kernel(
    const u16* __restrict__ A,     // y   [8192][1024] bf16
    const u16* __restrict__ B,     // Wout[1024][1024] bf16 (hi)
    float* __restrict__ C)         // out [8192][1024] fp32
{
    const int nt = blockIdx.x;   // 8
    const int mt = blockIdx.y;   // 64
    const int tid = threadIdx.x, wave = tid >> 6, lane = tid & 63;
    const int quad = lane >> 4, l16 = lane & 15;

    __shared__ __align__(16) u16 sA[128 * 32];
    __shared__ __align__(16) u16 sB[128 * 32];

    const int srow = lane >> 2, scol = (lane & 3) * 8;
    const size_t aoff = ((size_t)(mt * 128) + srow) * 1024 + scol;
    const size_t boff = ((size_t)(nt * 128) + srow) * 1024 + scol;
    const int r0 = wave * 16, r1 = 64 + wave * 16;

    float4_t acc[2][8];
#pragma unroll
    for (int i = 0; i < 2; ++i)
#pragma unroll
        for (int j = 0; j < 8; ++j) acc[i][j] = (float4_t)(0.f);

    for (int kt = 0; kt < 32; ++kt) {
        __syncthreads();
        const int kc0 = kt * 32;
        gl_lds16(A + aoff + (size_t)r0 * 1024 + kc0, &sA[r0 * 32]);
        gl_lds16(A + aoff + (size_t)r1 * 1024 + kc0, &sA[r1 * 32]);
        gl_lds16(B + boff + (size_t)r0 * 1024 + kc0, &sB[r0 * 32]);
        gl_lds16(B + boff + (size_t)r1 * 1024 + kc0, &sB[r1 * 32]);
        __syncthreads();

        short8 afr[2];
#pragma unroll
        for (int mi = 0; mi < 2; ++mi)
            afr[mi] = *(const short8*)(sA + (wave * 32 + mi * 16 + l16) * 32 + quad * 8);
#pragma unroll
        for (int ne = 0; ne < 8; ++ne) {
            short8 bfr = *(const short8*)(sB + (ne * 16 + l16) * 32 + quad * 8);
#pragma unroll
            for (int mi = 0; mi < 2; ++mi)
                acc[mi][ne] = __builtin_amdgcn_mfma_f32_16x16x32_bf16(afr[mi], bfr, acc[mi][ne], 0, 0, 0);
        }
    }

#pragma unroll
    for (int mi = 0; mi < 2; ++mi)
#pragma unroll
        for (int ne = 0; ne < 8; ++ne)
#pragma unroll
            for (int r = 0; r < 4; ++r) {
                int row = mt * 128 + wave * 32 + mi * 16 + quad * 4 + r;
                int col = nt * 128 + ne * 16 + l16;
                C[(size_t)row * D_ + col] = acc[mi][ne][r];
            }
}

// ---------------------------------------------------------------------------
extern "C" void kernel_launch(void* const* d_in, const int* in_sizes, int n_in,
                              void* d_out, int out_size, void* d_ws, size_t ws_size,
                              hipStream_t stream)
{
    const float* x   = (const float*)d_in[0];
    const int*   msk = (const int*)d_in[1];
    const float* Wq  = (const float*)d_in[2];
    const float* Wk  = (const float*)d_in[3];
    const float* Wv  = (const float*)d_in[4];
    const float* Wo  = (const float*)d_in[5];

    float* out  = (float*)d_out;                         // [4,2048,1024] fp32
    float* aout = out + (size_t)BS_ * N_ * D_;           // [4,2048,2048] fp32

    // transient split buffers in d_out (dead before attn/outgemm overwrite)
    u16* Whi  = (u16*)d_out;                       // 2048*1024
    u16* Wlo  = Whi  + (size_t)2048 * 1024;        // 2048*1024
    u16* Wvhi = Wlo  + (size_t)2048 * 1024;        // 1024*1024
    u16* Xhi  = Wvhi + (size_t)1024 * 1024;        // 8192*1024
    u16* Xlo  = Xhi  + (size_t)8192 * 1024;        // 8192*1024

    // workspace (111.4 MB)
    char* w = (char*)d_ws;
    u16* APt = (u16*)w;                       w += (size_t)N_ * N_ * 2;   // transposed AP
    const size_t szqk = (size_t)BS_ * H_ * N_ * DH_ * 2;
    u16* Qhi = (u16*)w; w += szqk;
    u16* Qlo = (u16*)w; w += szqk;
    u16* Khi = (u16*)w; w += szqk;
    u16* Klo = (u16*)w; w += szqk;
    u16* VT  = (u16*)w; w += szqk;
    float* lrow = (float*)w;                  w += (size_t)BS_ * H_ * N_ * 4;
    u16* Wohi = (u16*)w;                      w += (size_t)D_ * D_ * 2;
    u16* yb   = (u16*)w;                      w += (size_t)BS_ * N_ * D_ * 2;

    apt_kernel<<<8192, 256, 0, stream>>>((unsigned int*)APt);
    split_kernel<<<12288, 256, 0, stream>>>(x, Wq, Wk, Wv, Wo,
                                            Xhi, Xlo, Whi, Wlo, Wvhi, Wohi);
    qk_gemm<<<dim3(64, 16), 256, 0, stream>>>(Xhi, Xlo, Whi, Wlo,
                                              Qhi, Qlo, Khi, Klo);
    v_gemm<<<dim3(16, 32), 256, 0, stream>>>(Wvhi, Xhi, VT);
    rowstats_kernel<<<dim3(32, 32), 512, 0, stream>>>(Qhi, Qlo, Khi, Klo, APt, msk, lrow);
    attn_kernel<<<dim3(16, 32), 512, 0, stream>>>(Qhi, Qlo, Khi, Klo, VT, APt, msk,
                                                  lrow, yb, aout);
    outgemm_kernel<<<dim3(8, 64), 256, 0, stream>>>(yb, Wohi, out);
}

// Round 4
// 637.996 us; speedup vs baseline: 1.2907x; 1.0558x over previous
//
#include <hip/hip_runtime.h>
#include <math.h>

// Problem constants
#define BS_ 4
#define N_  2048
#define D_  1024
#define H_  8
#define DH_ 128

typedef __attribute__((ext_vector_type(8))) short short8;
typedef __attribute__((ext_vector_type(4))) short short4_t;
typedef __attribute__((ext_vector_type(4))) float float4_t;
typedef unsigned short u16;

__device__ __forceinline__ u16 f2bf(float f) {
    union { float f; unsigned u; } v; v.f = f;
    unsigned r = v.u + 0x7FFFu + ((v.u >> 16) & 1u);   // RNE
    return (u16)(r >> 16);
}
__device__ __forceinline__ float bf2f(u16 h) {
    union { unsigned u; float f; } v; v.u = ((unsigned)h) << 16;
    return v.f;
}
__device__ __forceinline__ void split4(float a, float b, float c, float d,
                                       short4_t* hi, short4_t* lo) {
    u16 h0 = f2bf(a), h1 = f2bf(b), h2 = f2bf(c), h3 = f2bf(d);
    (*hi)[0] = (short)h0; (*hi)[1] = (short)h1; (*hi)[2] = (short)h2; (*hi)[3] = (short)h3;
    (*lo)[0] = (short)f2bf(a - bf2f(h0));
    (*lo)[1] = (short)f2bf(b - bf2f(h1));
    (*lo)[2] = (short)f2bf(c - bf2f(h2));
    (*lo)[3] = (short)f2bf(d - bf2f(h3));
}

// async global->LDS, 16B per lane; LDS dest = wave-uniform base + lane*16.
__device__ __forceinline__ void gl_lds16(const void* g, void* l) {
    __builtin_amdgcn_global_load_lds(
        (const __attribute__((address_space(1))) unsigned int*)g,
        (__attribute__((address_space(3))) unsigned int*)l,
        16, 0, 0);
}

// ---------------------------------------------------------------------------
// Kernel 1: TRANSPOSED AP table, bf16.  APt[i][j] = AP[j][i].
// ---------------------------------------------------------------------------
__global__ void apt_kernel(unsigned int* __restrict__ APtw) {
    int idx = blockIdx.x * 256 + threadIdx.x;   // 2,097,152 = 2048 rows * 1024 words
    int i = idx >> 10;             // row (feature index) 0..2047
    int jw = idx & 1023;           // word within row; j0 = 2*jw
    int u = i >> 1;
    float ex = exp2f(-(float)u * (13.287712379549449f / 512.0f));
    float a0 = (float)(2 * jw) * ex;
    float a1 = (float)(2 * jw + 1) * ex;
    float v0, v1;
    if (i & 1) { v0 = cosf(a0); v1 = cosf(a1); }
    else       { v0 = sinf(a0); v1 = sinf(a1); }
    APtw[(size_t)i * (N_ / 2) + jw] = (unsigned)f2bf(v0) | ((unsigned)f2bf(v1) << 16);
}

// ---------------------------------------------------------------------------
// Kernel 2: fp32 -> bf16 hi/lo pre-split of X, Wq|Wk (cat), Wv (hi), Wout (hi).
// ---------------------------------------------------------------------------
__global__ void split_kernel(const float* __restrict__ x,
                             const float* __restrict__ Wq, const float* __restrict__ Wk,
                             const float* __restrict__ Wv, const float* __restrict__ Wo,
                             u16* __restrict__ Xhi, u16* __restrict__ Xlo,
                             u16* __restrict__ Whi, u16* __restrict__ Wlo,
                             u16* __restrict__ Wvhi, u16* __restrict__ Wohi) {
    int i = blockIdx.x * 256 + threadIdx.x;            // 3,145,728 float4s
    const float* src; u16 *dhi, *dlo; size_t off;
    if (i < 2097152)      { src = x  + 4*(size_t)i;             dhi = Xhi;  dlo = Xlo;  off = 4*(size_t)i; }
    else if (i < 2359296) { size_t j = i - 2097152; src = Wq + 4*j; dhi = Whi; dlo = Wlo; off = 4*j; }
    else if (i < 2621440) { size_t j = i - 2359296; src = Wk + 4*j; dhi = Whi; dlo = Wlo; off = 1048576 + 4*j; }
    else if (i < 2883584) { size_t j = i - 2621440; src = Wv + 4*j; dhi = Wvhi; dlo = nullptr; off = 4*j; }
    else                  { size_t j = i - 2883584; src = Wo + 4*j; dhi = Wohi; dlo = nullptr; off = 4*j; }
    float4 v = *(const float4*)src;
    short4_t hi, lo;
    split4(v.x, v.y, v.z, v.w, &hi, &lo);
    *(short4_t*)(dhi + off) = hi;
    if (dlo) *(short4_t*)(dlo + off) = lo;
}

// ---------------------------------------------------------------------------
// Kernel 3: Q,K projections.  3-term bf16 split, m97 structure (unchanged).
// ---------------------------------------------------------------------------
__global__ __launch_bounds__(256, 4) void qk_gemm(
    const u16* __restrict__ Xhi, const u16* __restrict__ Xlo,
    const u16* __restrict__ Whi, const u16* __restrict__ Wlo,
    u16* __restrict__ Qhi, u16* __restrict__ Qlo,
    u16* __restrict__ Khi, u16* __restrict__ Klo)
{
    const int mt = blockIdx.x;   // 64
    const int nt = blockIdx.y;   // 16
    const int tid = threadIdx.x, wave = tid >> 6, lane = tid & 63;
    const int quad = lane >> 4, l16 = lane & 15;

    __shared__ __align__(16) u16 sA[2][128 * 32];
    __shared__ __align__(16) u16 sB[2][128 * 32];

    const int srow = lane >> 2;
    const int scol = (lane & 3) * 8;
    const size_t aoff = ((size_t)(mt * 128) + srow) * 1024 + scol;
    const size_t boff = ((size_t)(nt * 128) + srow) * 1024 + scol;
    const int r0 = wave * 16, r1 = 64 + wave * 16;

    float4_t acc[2][8];
#pragma unroll
    for (int i = 0; i < 2; ++i)
#pragma unroll
        for (int j = 0; j < 8; ++j) acc[i][j] = (float4_t)(0.f);

    for (int kt = 0; kt < 32; ++kt) {
        __syncthreads();
        const int kc0 = kt * 32;
        gl_lds16(Xhi + aoff + (size_t)r0 * 1024 + kc0, &sA[0][r0 * 32]);
        gl_lds16(Xhi + aoff + (size_t)r1 * 1024 + kc0, &sA[0][r1 * 32]);
        gl_lds16(Xlo + aoff + (size_t)r0 * 1024 + kc0, &sA[1][r0 * 32]);
        gl_lds16(Xlo + aoff + (size_t)r1 * 1024 + kc0, &sA[1][r1 * 32]);
        gl_lds16(Whi + boff + (size_t)r0 * 1024 + kc0, &sB[0][r0 * 32]);
        gl_lds16(Whi + boff + (size_t)r1 * 1024 + kc0, &sB[0][r1 * 32]);
        gl_lds16(Wlo + boff + (size_t)r0 * 1024 + kc0, &sB[1][r0 * 32]);
        gl_lds16(Wlo + boff + (size_t)r1 * 1024 + kc0, &sB[1][r1 * 32]);
        __syncthreads();

#pragma unroll
        for (int t = 0; t < 3; ++t) {
            const u16* As = sA[t == 2 ? 1 : 0];
            const u16* Bs = sB[t == 1 ? 1 : 0];
            short8 afr[2];
#pragma unroll
            for (int mi = 0; mi < 2; ++mi)
                afr[mi] = *(const short8*)(As + (wave * 32 + mi * 16 + l16) * 32 + quad * 8);
#pragma unroll
            for (int ne = 0; ne < 8; ++ne) {
                short8 bfr = *(const short8*)(Bs + (ne * 16 + l16) * 32 + quad * 8);
#pragma unroll
                for (int mi = 0; mi < 2; ++mi)
                    acc[mi][ne] = __builtin_amdgcn_mfma_f32_16x16x32_bf16(afr[mi], bfr, acc[mi][ne], 0, 0, 0);
            }
        }
    }

    const int b = mt >> 4, q0 = (mt & 15) * 128;
    const bool isQ = (nt < 8);
    u16* Hi = isQ ? Qhi : Khi;
    u16* Lo = isQ ? Qlo : Klo;
    const int h = isQ ? nt : nt - 8;
    const size_t base = (size_t)(b * 8 + h) * N_ * DH_;
#pragma unroll
    for (int mi = 0; mi < 2; ++mi)
#pragma unroll
        for (int ne = 0; ne < 8; ++ne)
#pragma unroll
            for (int r = 0; r < 4; ++r) {
                int q = q0 + wave * 32 + mi * 16 + quad * 4 + r;
                int e = ne * 16 + l16;
                float v = acc[mi][ne][r];
                u16 hv = f2bf(v);
                Hi[base + (size_t)q * DH_ + e] = hv;
                Lo[base + (size_t)q * DH_ + e] = f2bf(v - bf2f(hv));
            }
}

// ---------------------------------------------------------------------------
// Kernel 4: V^T[bh][e][q]  (1-term bf16, unchanged).
// ---------------------------------------------------------------------------
__global__ __launch_bounds__(256, 4) void v_gemm(
    const u16* __restrict__ Wvhi, const u16* __restrict__ Xhi,
    u16* __restrict__ VT)
{
    const int qt = blockIdx.x;   // 16
    const int bh = blockIdx.y;   // 32
    const int b = bh >> 3, h = bh & 7;
    const int tid = threadIdx.x, wave = tid >> 6, lane = tid & 63;
    const int quad = lane >> 4, l16 = lane & 15;

    __shared__ __align__(16) u16 sA[128 * 32];
    __shared__ __align__(16) u16 sB[128 * 32];

    const int srow = lane >> 2, scol = (lane & 3) * 8;
    const size_t aoff = ((size_t)(h * 128) + srow) * 1024 + scol;
    const size_t boff = ((size_t)(b * N_ + qt * 128) + srow) * 1024 + scol;
    const int r0 = wave * 16, r1 = 64 + wave * 16;

    float4_t acc[2][8];
#pragma unroll
    for (int i = 0; i < 2; ++i)
#pragma unroll
        for (int j = 0; j < 8; ++j) acc[i][j] = (float4_t)(0.f);

    for (int kt = 0; kt < 32; ++kt) {
        __syncthreads();
        const int kc0 = kt * 32;
        gl_lds16(Wvhi + aoff + (size_t)r0 * 1024 + kc0, &sA[r0 * 32]);
        gl_lds16(Wvhi + aoff + (size_t)r1 * 1024 + kc0, &sA[r1 * 32]);
        gl_lds16(Xhi  + boff + (size_t)r0 * 1024 + kc0, &sB[r0 * 32]);
        gl_lds16(Xhi  + boff + (size_t)r1 * 1024 + kc0, &sB[r1 * 32]);
        __syncthreads();

        short8 afr[2];
#pragma unroll
        for (int mi = 0; mi < 2; ++mi)
            afr[mi] = *(const short8*)(sA + (wave * 32 + mi * 16 + l16) * 32 + quad * 8);
#pragma unroll
        for (int ne = 0; ne < 8; ++ne) {
            short8 bfr = *(const short8*)(sB + (ne * 16 + l16) * 32 + quad * 8);
#pragma unroll
            for (int mi = 0; mi < 2; ++mi)
                acc[mi][ne] = __builtin_amdgcn_mfma_f32_16x16x32_bf16(afr[mi], bfr, acc[mi][ne], 0, 0, 0);
        }
    }

    u16* Cg = VT + (size_t)bh * DH_ * N_;
#pragma unroll
    for (int mi = 0; mi < 2; ++mi)
#pragma unroll
        for (int ne = 0; ne < 8; ++ne)
#pragma unroll
            for (int r = 0; r < 4; ++r) {
                int e = wave * 32 + mi * 16 + quad * 4 + r;
                int q = qt * 128 + ne * 16 + l16;
                Cg[(size_t)e * N_ + q] = f2bf(acc[mi][ne][r]);
            }
}

// ---------------------------------------------------------------------------
// Kernel 5 (pass A): l_j = sum_k exp(E[j,k]).  512 thr / 8 waves.
// This round: MFMA accumulator CHAIN SPLIT (kc01 / kc23 halves, summed at
// end) — depth 12 -> 6, independent chains 2 -> 4.  Mirrored bit-exactly in
// attn MFMA1.  setprio around the MFMA cluster.
// ---------------------------------------------------------------------------
__global__ __launch_bounds__(512, 4) void rowstats_kernel(
    const u16* __restrict__ Qhi, const u16* __restrict__ Qlo,
    const u16* __restrict__ Khi, const u16* __restrict__ Klo,
    const u16* __restrict__ APt,
    const int* __restrict__ mask,
    float* __restrict__ lrow)
{
    const int jt = blockIdx.x;    // 32 j-tiles of 64
    const int bh = blockIdx.y;    // 32
    const int b = bh >> 3;
    const int tid = threadIdx.x, wave = tid >> 6, lane = tid & 63;
    const int quad = lane >> 4, l16 = lane & 15;
    const int jsub = (wave & 3) * 16, khalf = wave >> 2;

    __shared__ __align__(16) u16 ldsK[2][64 * 264];    // streamed, split (66 KB)
    __shared__ int   s_mk[2][64];
    __shared__ float psum[64 * 2];

    // Q fragments resident in registers (8 x short8 = 32 VGPR)
    short8 rQh[4], rQl[4];
    {
        const size_t qrow = ((size_t)bh * N_ + (size_t)(jt * 64 + jsub + l16)) * DH_;
#pragma unroll
        for (int kc = 0; kc < 4; ++kc) {
            rQh[kc] = *(const short8*)(Qhi + qrow + kc * 32 + quad * 8);
            rQl[kc] = *(const short8*)(Qlo + qrow + kc * 32 + quad * 8);
        }
    }

    // per-lane AP base: row = key index (khalf*32 + nk*16 + l16), col fixed
    const u16* ap_base = APt + (size_t)(khalf * 32 + l16) * N_ + jt * 64 + jsub + quad * 4;
    short4_t apc[2];
#pragma unroll
    for (int nk = 0; nk < 2; ++nk)
        apc[nk] = *(const short4_t*)(ap_base + (size_t)(nk * 16) * N_);

    // buf0: K tile 0 + mask
    {
        const size_t Kb = ((size_t)bh * N_) * DH_;
        for (int c = tid; c < 2048; c += 512) {
            int row = c >> 5, half = (c >> 4) & 1, seg = c & 15;
            *(short8*)(ldsK[0] + row * 264 + half * 128 + seg * 8) =
                *(const short8*)((half ? Klo : Khi) + Kb + (size_t)row * DH_ + seg * 8);
        }
        if (tid < 64) s_mk[0][tid] = mask[b * N_ + tid];
    }

    float p[4] = {0.f, 0.f, 0.f, 0.f};
    int mj_on[4];
#pragma unroll
    for (int r = 0; r < 4; ++r)
        mj_on[r] = mask[b * N_ + jt * 64 + jsub + quad * 4 + r];

    __syncthreads();

    for (int kt = 0; kt < 32; ++kt) {
        const int cur = kt & 1, nxt = cur ^ 1;
        short8 rK[4];
        short4_t apn[2];
        int rmk = 0;
        if (kt < 31) {
            const size_t Kb2 = ((size_t)bh * N_ + (size_t)(kt + 1) * 64) * DH_;
#pragma unroll
            for (int i = 0; i < 4; ++i) {
                int c = tid + i * 512;
                int row = c >> 5, half = (c >> 4) & 1, seg = c & 15;
                rK[i] = *(const short8*)((half ? Klo : Khi) + Kb2 + (size_t)row * DH_ + seg * 8);
            }
#pragma unroll
            for (int nk = 0; nk < 2; ++nk)
                apn[nk] = *(const short4_t*)(ap_base + (size_t)((kt + 1) * 64 + nk * 16) * N_);
            if (tid < 64) rmk = mask[b * N_ + (kt + 1) * 64 + tid];
        }

        // MFMA: S[16 j][32 k per wave], kc-major, chain split kc01/kc23
        float4_t accA[2][2];   // [half][nk]
#pragma unroll
        for (int hf = 0; hf < 2; ++hf) {
            accA[hf][0] = (float4_t)(0.f); accA[hf][1] = (float4_t)(0.f);
        }
        __builtin_amdgcn_s_setprio(1);
#pragma unroll
        for (int kc = 0; kc < 4; ++kc) {
            const int hf = kc >> 1;
            short8 bH[2], bL[2];
#pragma unroll
            for (int nk = 0; nk < 2; ++nk)
                bH[nk] = *(const short8*)(ldsK[cur] + (khalf * 32 + nk * 16 + l16) * 264 + kc * 32 + quad * 8);
#pragma unroll
            for (int nk = 0; nk < 2; ++nk)
                accA[hf][nk] = __builtin_amdgcn_mfma_f32_16x16x32_bf16(rQh[kc], bH[nk], accA[hf][nk], 0, 0, 0);
#pragma unroll
            for (int nk = 0; nk < 2; ++nk)
                accA[hf][nk] = __builtin_amdgcn_mfma_f32_16x16x32_bf16(rQl[kc], bH[nk], accA[hf][nk], 0, 0, 0);
#pragma unroll
            for (int nk = 0; nk < 2; ++nk)
                bL[nk] = *(const short8*)(ldsK[cur] + (khalf * 32 + nk * 16 + l16) * 264 + 128 + kc * 32 + quad * 8);
#pragma unroll
            for (int nk = 0; nk < 2; ++nk)
                accA[hf][nk] = __builtin_amdgcn_mfma_f32_16x16x32_bf16(rQh[kc], bL[nk], accA[hf][nk], 0, 0, 0);
        }
        __builtin_amdgcn_s_setprio(0);
        float4_t acc[2];
        acc[0] = accA[0][0] + accA[1][0];
        acc[1] = accA[0][1] + accA[1][1];

#pragma unroll
        for (int nk = 0; nk < 2; ++nk) {
            int kk = khalf * 32 + nk * 16 + l16;
            int mk = s_mk[cur][kk];
#pragma unroll
            for (int r = 0; r < 4; ++r) {
                float e = acc[nk][r] + bf2f((u16)apc[nk][r]);
                e = (mj_on[r] && mk) ? e : -1.0e9f;
                p[r] += __expf(e);
            }
        }

        if (kt < 31) {
#pragma unroll
            for (int i = 0; i < 4; ++i) {
                int c = tid + i * 512;
                int row = c >> 5, half = (c >> 4) & 1, seg = c & 15;
                *(short8*)(ldsK[nxt] + row * 264 + half * 128 + seg * 8) = rK[i];
            }
            if (tid < 64) s_mk[nxt][tid] = rmk;
            apc[0] = apn[0]; apc[1] = apn[1];
        }
        __syncthreads();
    }

    // reduce over l16 lanes, then over the two k-half waves
#pragma unroll
    for (int r = 0; r < 4; ++r) {
        float s = p[r];
        for (int off = 1; off < 16; off <<= 1)
            s += __shfl_xor(s, off, 64);
        if (l16 == 0)
            psum[(jsub + quad * 4 + r) * 2 + khalf] = s;
    }
    __syncthreads();
    if (tid < 64)
        lrow[(size_t)bh * N_ + jt * 64 + tid] = psum[tid * 2] + psum[tid * 2 + 1];
}

// ---------------------------------------------------------------------------
// Kernel 6 (pass B): y[i,e] = sum_j A[j,i] V[j,e], A = exp(E)/l_j.
// 512 thr / 8 waves.  This round (latency attack):
//  - JBLK 32 -> 64: iterations 64 -> 32, barriers halved, MFMA clusters 2x.
//  - MFMA1 chain split (kc01/kc23 accumulator halves summed at end), depth
//    12 -> 6, 8 independent chains; MIRRORED bit-exactly in rowstats.
//  - Wave = iq (i-quarter, 32 i in K-regs) x jh (j-half, 32 j).
//  - V staged via async global_load_lds with XOR swizzle (linear dest,
//    inverse-swizzled per-lane SOURCE, swizzled read): group ^= e&7.
//  - setprio around MFMA clusters.
// LDS 119.3 KB -> 1 block/CU (occupancy was proven worthless in R2/R3).
// ---------------------------------------------------------------------------
__global__ __launch_bounds__(512, 2) void attn_kernel(
    const u16* __restrict__ Qhi, const u16* __restrict__ Qlo,
    const u16* __restrict__ Khi, const u16* __restrict__ Klo,
    const u16* __restrict__ VT,
    const u16* __restrict__ APt,
    const int* __restrict__ mask,
    const float* __restrict__ lrow,
    u16* __restrict__ yout,               // [BS,N,D] bf16 (ws)
    float* __restrict__ aout)             // [BS,N,N] fp32 (d_out tail)
{
    const int it = blockIdx.x;   // 16 i-tiles (keys)
    const int bh = blockIdx.y;   // 32
    const int b = bh >> 3, h = bh & 7;
    const int tid = threadIdx.x, wave = tid >> 6, lane = tid & 63;  // 8 waves
    const int quad = lane >> 4, l16 = lane & 15;

    __shared__ __align__(16) u16 ldsQ[2][64 * 264];    // Q_j split, dbuf (67.6 KB)
    __shared__ __align__(16) u16 ldsV[2][128 * 64];    // V^T [e][j] swz, dbuf (32 KB, DMA)
    __shared__ __align__(16) u16 ldsA[128 * 72];       // A^T [i][j]      (18.4 KB)
    __shared__ __align__(16) float s_g[2][64];         // per-j: dead?-1:1/l

    // wave mapping: iq = i-quarter (MFMA1 K-rows, MFMA2 i-pod), jh = j-half /
    // e-half
    const int iq = wave >> 1, jh = wave & 1;
    const int igv0 = it * 128 + iq * 32 + l16;         // ih = 0
    const int igv1 = igv0 + 16;                        // ih = 1
    const size_t vbase = (size_t)bh * DH_ * N_;

    // K fragments resident in registers: 32 i rows/wave (16 x short8 = 64 VGPR)
    short8 rKh[4][2], rKl[4][2];
    {
        const size_t kr0 = ((size_t)bh * N_ + igv0) * DH_;
        const size_t kr1 = ((size_t)bh * N_ + igv1) * DH_;
#pragma unroll
        for (int kc = 0; kc < 4; ++kc) {
            rKh[kc][0] = *(const short8*)(Khi + kr0 + kc * 32 + quad * 8);
            rKh[kc][1] = *(const short8*)(Khi + kr1 + kc * 32 + quad * 8);
            rKl[kc][0] = *(const short8*)(Klo + kr0 + kc * 32 + quad * 8);
            rKl[kc][1] = *(const short8*)(Klo + kr1 + kc * 32 + quad * 8);
        }
    }

    // per-lane AP base: row = i (fixed per ih), col walks with jt
    const u16* apb0 = APt + (size_t)igv0 * N_ + jh * 32 + quad * 4;
    const u16* apb1 = APt + (size_t)igv1 * N_ + jh * 32 + quad * 4;
    short4_t apc[2][2];   // [ih][mj]
#pragma unroll
    for (int mj = 0; mj < 2; ++mj) {
        apc[0][mj] = *(const short4_t*)(apb0 + mj * 16);
        apc[1][mj] = *(const short4_t*)(apb1 + mj * 16);
    }

    const int ion0 = mask[b * N_ + igv0];
    const int ion1 = mask[b * N_ + igv1];

    // buf0 (jt = 0)
    {
        const size_t Qb0 = ((size_t)bh * N_) * DH_;
        for (int c = tid; c < 2048; c += 512) {
            int row = c >> 5, half = (c >> 4) & 1, seg = c & 15;
            *(short8*)(ldsQ[0] + row * 264 + half * 128 + seg * 8) =
                *(const short8*)((half ? Qlo : Qhi) + Qb0 + (size_t)row * DH_ + seg * 8);
        }
#pragma unroll
        for (int i = 0; i < 2; ++i) {
            int c = i * 512 + wave * 64 + lane;
            int e = c >> 3, g = c & 7;
            gl_lds16(VT + vbase + (size_t)e * N_ + ((g ^ (e & 7)) * 8),
                     ldsV[0] + (size_t)(i * 512 + wave * 64) * 8);
        }
        if (tid < 64) {
            float l = lrow[(size_t)bh * N_ + tid];
            int mj = mask[b * N_ + tid];
            s_g[0][tid] = (mj && l > 0.f) ? 1.0f / l : -1.0f;
        }
    }

    float4_t accy[2][4];   // [ni][ne]: i = iq*32+ni*16.., e = jh*64+ne*16..
#pragma unroll
    for (int ni = 0; ni < 2; ++ni)
#pragma unroll
        for (int ne = 0; ne < 4; ++ne) accy[ni][ne] = (float4_t)(0.f);

    const bool do_aout = (h == 7);
    const float inv_n = 1.0f / (float)N_;

    __syncthreads();

    for (int jt = 0; jt < 32; ++jt) {
        const int cur = jt & 1, nxt = cur ^ 1;
        const int j0 = jt * 64;

        // prefetch next j-tile (V via swizzled async DMA into ldsV[nxt];
        // Q/AP/g into registers)
        short8 rQ[4];
        short4_t apn[2][2];
        float r_g = 0.f;
        if (jt < 31) {
            const int j0n = j0 + 64;
#pragma unroll
            for (int i = 0; i < 2; ++i) {
                int c = i * 512 + wave * 64 + lane;
                int e = c >> 3, g = c & 7;
                gl_lds16(VT + vbase + (size_t)e * N_ + j0n + ((g ^ (e & 7)) * 8),
                         ldsV[nxt] + (size_t)(i * 512 + wave * 64) * 8);
            }
            const size_t Qb2 = ((size_t)bh * N_ + j0n) * DH_;
#pragma unroll
            for (int i = 0; i < 4; ++i) {
                int c = tid + i * 512;
                int row = c >> 5, half = (c >> 4) & 1, seg = c & 15;
                rQ[i] = *(const short8*)((half ? Qlo : Qhi) + Qb2 + (size_t)row * DH_ + seg * 8);
            }
#pragma unroll
            for (int mj = 0; mj < 2; ++mj) {
                apn[0][mj] = *(const short4_t*)(apb0 + j0n + mj * 16);
                apn[1][mj] = *(const short4_t*)(apb1 + j0n + mj * 16);
            }
            if (tid < 64) {
                float l = lrow[(size_t)bh * N_ + j0n + tid];
                int mj = mask[b * N_ + j0n + tid];
                r_g = (mj && l > 0.f) ? 1.0f / l : -1.0f;
            }
        }

        // MFMA1: S[j 32 (wave's half)][i 32] — kc-major, chain split kc01/kc23,
        // per-acc order (Qhi*Khi, Qlo*Khi, Qhi*Klo) bitwise-matches rowstats
        float4_t accsA[2][2][2];   // [half][mj][ih]
#pragma unroll
        for (int hf = 0; hf < 2; ++hf)
#pragma unroll
            for (int mj = 0; mj < 2; ++mj)
#pragma unroll
                for (int ih = 0; ih < 2; ++ih) accsA[hf][mj][ih] = (float4_t)(0.f);

        __builtin_amdgcn_s_setprio(1);
#pragma unroll
        for (int kc = 0; kc < 4; ++kc) {
            const int hf = kc >> 1;
            short8 aH[2], aL[2];
#pragma unroll
            for (int mj = 0; mj < 2; ++mj)
                aH[mj] = *(const short8*)(ldsQ[cur] + (jh * 32 + mj * 16 + l16) * 264 + kc * 32 + quad * 8);
#pragma unroll
            for (int mj = 0; mj < 2; ++mj)
#pragma unroll
                for (int ih = 0; ih < 2; ++ih)
                    accsA[hf][mj][ih] = __builtin_amdgcn_mfma_f32_16x16x32_bf16(aH[mj], rKh[kc][ih], accsA[hf][mj][ih], 0, 0, 0);
#pragma unroll
            for (int mj = 0; mj < 2; ++mj)
                aL[mj] = *(const short8*)(ldsQ[cur] + (jh * 32 + mj * 16 + l16) * 264 + 128 + kc * 32 + quad * 8);
#pragma unroll
            for (int mj = 0; mj < 2; ++mj)
#pragma unroll
                for (int ih = 0; ih < 2; ++ih)
                    accsA[hf][mj][ih] = __builtin_amdgcn_mfma_f32_16x16x32_bf16(aL[mj], rKh[kc][ih], accsA[hf][mj][ih], 0, 0, 0);
#pragma unroll
            for (int mj = 0; mj < 2; ++mj)
#pragma unroll
                for (int ih = 0; ih < 2; ++ih)
                    accsA[hf][mj][ih] = __builtin_amdgcn_mfma_f32_16x16x32_bf16(aH[mj], rKl[kc][ih], accsA[hf][mj][ih], 0, 0, 0);
        }
        __builtin_amdgcn_s_setprio(0);

        // A = exp(E)*g (g<0 -> dead row -> 1/N); write A^T to LDS; h==7: fp32 out
#pragma unroll
        for (int mj = 0; mj < 2; ++mj) {
            float4_t g4 = *(const float4_t*)(&s_g[cur][jh * 32 + mj * 16 + quad * 4]);
#pragma unroll
            for (int ih = 0; ih < 2; ++ih) {
                float4_t accs = accsA[0][mj][ih] + accsA[1][mj][ih];
                const int ig = ih ? igv1 : igv0;
                const int ion = ih ? ion1 : ion0;
                short4_t pk;
#pragma unroll
                for (int r = 0; r < 4; ++r) {
                    int jl = jh * 32 + mj * 16 + quad * 4 + r;
                    float e = accs[r] + bf2f((u16)apc[ih][mj][r]);
                    float g = g4[r];
                    float a = (g < 0.f) ? inv_n : (ion ? __expf(e) * g : 0.f);
                    pk[r] = (short)f2bf(a);
                    if (do_aout)
                        aout[((size_t)(b * N_ + j0 + jl)) * N_ + ig] = a;
                }
                *(short4_t*)(ldsA + (size_t)(iq * 32 + ih * 16 + l16) * 72 + jh * 32 + mj * 16 + quad * 4) = pk;
            }
        }
        __syncthreads();   // B1: ldsA ready; reads of ldsQ[cur] done

        // MFMA2: y[i(32 per pod), e(64 per half)] += A^T · V   (k = 64)
        {
            short8 afrA[2][2];
#pragma unroll
            for (int ni = 0; ni < 2; ++ni)
#pragma unroll
                for (int ks = 0; ks < 2; ++ks)
                    afrA[ni][ks] = *(const short8*)(ldsA + (iq * 32 + ni * 16 + l16) * 72 + ks * 32 + quad * 8);
            __builtin_amdgcn_s_setprio(1);
#pragma unroll
            for (int ne = 0; ne < 4; ++ne) {
#pragma unroll
                for (int ks = 0; ks < 2; ++ks) {
                    short8 bfr = *(const short8*)(ldsV[cur] + (size_t)(jh * 64 + ne * 16 + l16) * 64 +
                                                  (((ks * 4 + quad) ^ (l16 & 7)) * 8));
#pragma unroll
                    for (int ni = 0; ni < 2; ++ni)
                        accy[ni][ne] = __builtin_amdgcn_mfma_f32_16x16x32_bf16(afrA[ni][ks], bfr, accy[ni][ne], 0, 0, 0);
                }
            }
            __builtin_amdgcn_s_setprio(0);
        }

        if (jt < 31) {
#pragma unroll
            for (int i = 0; i < 4; ++i) {
                int c = tid + i * 512;
                int row = c >> 5, half = (c >> 4) & 1, seg = c & 15;
                *(short8*)(ldsQ[nxt] + row * 264 + half * 128 + seg * 8) = rQ[i];
            }
            if (tid < 64) s_g[nxt][tid] = r_g;
#pragma unroll
            for (int mj = 0; mj < 2; ++mj) {
                apc[0][mj] = apn[0][mj];
                apc[1][mj] = apn[1][mj];
            }
        }
        __syncthreads();   // B2: buf[nxt] ready (incl. V DMA drain); ldsA reads done
    }

#pragma unroll
    for (int ni = 0; ni < 2; ++ni)
#pragma unroll
        for (int ne = 0; ne < 4; ++ne)
#pragma unroll
            for (int r = 0; r < 4; ++r) {
                int irow = iq * 32 + ni * 16 + quad * 4 + r;
                int e = jh * 64 + ne * 16 + l16;
                yout[((size_t)b * N_ + it * 128 + irow) * D_ + h * DH_ + e] =
                    f2bf(accy[ni][ne][r]);
            }
}

// ---------------------------------------------------------------------------
// Kernel 7: out[m,o] = sum_d y[m,d] Wout[o,d]  (unchanged).
// ---------------------------------------------------------------------------
__global__ __launch_bounds__(256, 4) void outgemm_kernel(
    const u16* __restrict__ A,     // y   [8192][1024] bf16
    const u16* __restrict__ B,     // Wout[1024][1024] bf16 (hi)
    float* __restrict__ C)         // out [8192][1024] fp32
{
    const int nt = blockIdx.x;   // 8
    const int mt = blockIdx.y;   // 64
    const int tid = threadIdx.x, wave = tid >> 6, lane = tid & 63;
    const int quad = lane >> 4, l16 = lane & 15;

    __shared__ __align__(16) u16 sA[128 * 32];
    __shared__ __align__(16) u16 sB[128 * 32];

    const int srow = lane >> 2, scol = (lane & 3) * 8;
    const size_t aoff = ((size_t)(mt * 128) + srow) * 1024 + scol;
    const size_t boff = ((size_t)(nt * 128) + srow) * 1024 + scol;
    const int r0 = wave * 16, r1 = 64 + wave * 16;

    float4_t acc[2][8];
#pragma unroll
    for (int i = 0; i < 2; ++i)
#pragma unroll
        for (int j = 0; j < 8; ++j) acc[i][j] = (float4_t)(0.f);

    for (int kt = 0; kt < 32; ++kt) {
        __syncthreads();
        const int kc0 = kt * 32;
        gl_lds16(A + aoff + (size_t)r0 * 1024 + kc0, &sA[r0 * 32]);
        gl_lds16(A + aoff + (size_t)r1 * 1024 + kc0, &sA[r1 * 32]);
        gl_lds16(B + boff + (size_t)r0 * 1024 + kc0, &sB[r0 * 32]);
        gl_lds16(B + boff + (size_t)r1 * 1024 + kc0, &sB[r1 * 32]);
        __syncthreads();

        short8 afr[2];
#pragma unroll
        for (int mi = 0; mi < 2; ++mi)
            afr[mi] = *(const short8*)(sA + (wave * 32 + mi * 16 + l16) * 32 + quad * 8);
#pragma unroll
        for (int ne = 0; ne < 8; ++ne) {
            short8 bfr = *(const short8*)(sB + (ne * 16 + l16) * 32 + quad * 8);
#pragma unroll
            for (int mi = 0; mi < 2; ++mi)
                acc[mi][ne] = __builtin_amdgcn_mfma_f32_16x16x32_bf16(afr[mi], bfr, acc[mi][ne], 0, 0, 0);
        }
    }

#pragma unroll
    for (int mi = 0; mi < 2; ++mi)
#pragma unroll
        for (int ne = 0; ne < 8; ++ne)
#pragma unroll
            for (int r = 0; r < 4; ++r) {
                int row = mt * 128 + wave * 32 + mi * 16 + quad * 4 + r;
                int col = nt * 128 + ne * 16 + l16;
                C[(size_t)row * D_ + col] = acc[mi][ne][r];
            }
}

// ---------------------------------------------------------------------------
extern "C" void kernel_launch(void* const* d_in, const int* in_sizes, int n_in,
                              void* d_out, int out_size, void* d_ws, size_t ws_size,
                              hipStream_t stream)
{
    const float* x   = (const float*)d_in[0];
    const int*   msk = (const int*)d_in[1];
    const float* Wq  = (const float*)d_in[2];
    const float* Wk  = (const float*)d_in[3];
    const float* Wv  = (const float*)d_in[4];
    const float* Wo  = (const float*)d_in[5];

    float* out  = (float*)d_out;                         // [4,2048,1024] fp32
    float* aout = out + (size_t)BS_ * N_ * D_;           // [4,2048,2048] fp32

    // transient split buffers in d_out (dead before attn/outgemm overwrite)
    u16* Whi  = (u16*)d_out;                       // 2048*1024
    u16* Wlo  = Whi  + (size_t)2048 * 1024;        // 2048*1024
    u16* Wvhi = Wlo  + (size_t)2048 * 1024;        // 1024*1024
    u16* Xhi  = Wvhi + (size_t)1024 * 1024;        // 8192*1024
    u16* Xlo  = Xhi  + (size_t)8192 * 1024;        // 8192*1024

    // workspace (111.4 MB)
    char* w = (char*)d_ws;
    u16* APt = (u16*)w;                       w += (size_t)N_ * N_ * 2;   // transposed AP
    const size_t szqk = (size_t)BS_ * H_ * N_ * DH_ * 2;
    u16* Qhi = (u16*)w; w += szqk;
    u16* Qlo = (u16*)w; w += szqk;
    u16* Khi = (u16*)w; w += szqk;
    u16* Klo = (u16*)w; w += szqk;
    u16* VT  = (u16*)w; w += szqk;
    float* lrow = (float*)w;                  w += (size_t)BS_ * H_ * N_ * 4;
    u16* Wohi = (u16*)w;                      w += (size_t)D_ * D_ * 2;
    u16* yb   = (u16*)w;                      w += (size_t)BS_ * N_ * D_ * 2;

    apt_kernel<<<8192, 256, 0, stream>>>((unsigned int*)APt);
    split_kernel<<<12288, 256, 0, stream>>>(x, Wq, Wk, Wv, Wo,
                                            Xhi, Xlo, Whi, Wlo, Wvhi, Wohi);
    qk_gemm<<<dim3(64, 16), 256, 0, stream>>>(Xhi, Xlo, Whi, Wlo,
                                              Qhi, Qlo, Khi, Klo);
    v_gemm<<<dim3(16, 32), 256, 0, stream>>>(Wvhi, Xhi, VT);
    rowstats_kernel<<<dim3(32, 32), 512, 0, stream>>>(Qhi, Qlo, Khi, Klo, APt, msk, lrow);
    attn_kernel<<<dim3(16, 32), 512, 0, stream>>>(Qhi, Qlo, Khi, Klo, VT, APt, msk,
                                                  lrow, yb, aout);
    outgemm_kernel<<<dim3(8, 64), 256, 0, stream>>>(yb, Wohi, out);
}

// Round 6
// 619.075 us; speedup vs baseline: 1.3301x; 1.0306x over previous
//
#include <hip/hip_runtime.h>
#include <math.h>

// Problem constants
#define BS_ 4
#define N_  2048
#define D_  1024
#define H_  8
#define DH_ 128

typedef __attribute__((ext_vector_type(8))) short short8;
typedef __attribute__((ext_vector_type(4))) short short4_t;
typedef __attribute__((ext_vector_type(4))) float float4_t;
typedef unsigned short u16;

__device__ __forceinline__ u16 f2bf(float f) {
    union { float f; unsigned u; } v; v.f = f;
    unsigned r = v.u + 0x7FFFu + ((v.u >> 16) & 1u);   // RNE
    return (u16)(r >> 16);
}
__device__ __forceinline__ float bf2f(u16 h) {
    union { unsigned u; float f; } v; v.u = ((unsigned)h) << 16;
    return v.f;
}
__device__ __forceinline__ void split4(float a, float b, float c, float d,
                                       short4_t* hi, short4_t* lo) {
    u16 h0 = f2bf(a), h1 = f2bf(b), h2 = f2bf(c), h3 = f2bf(d);
    (*hi)[0] = (short)h0; (*hi)[1] = (short)h1; (*hi)[2] = (short)h2; (*hi)[3] = (short)h3;
    (*lo)[0] = (short)f2bf(a - bf2f(h0));
    (*lo)[1] = (short)f2bf(b - bf2f(h1));
    (*lo)[2] = (short)f2bf(c - bf2f(h2));
    (*lo)[3] = (short)f2bf(d - bf2f(h3));
}

// async global->LDS, 16B per lane; LDS dest = wave-uniform base + lane*16.
__device__ __forceinline__ void gl_lds16(const void* g, void* l) {
    __builtin_amdgcn_global_load_lds(
        (const __attribute__((address_space(1))) unsigned int*)g,
        (__attribute__((address_space(3))) unsigned int*)l,
        16, 0, 0);
}

// ---------------------------------------------------------------------------
// Kernel 1: TRANSPOSED AP table, bf16.  APt[i][j] = AP[j][i].
// ---------------------------------------------------------------------------
__global__ void apt_kernel(unsigned int* __restrict__ APtw) {
    int idx = blockIdx.x * 256 + threadIdx.x;   // 2,097,152 = 2048 rows * 1024 words
    int i = idx >> 10;             // row (feature index) 0..2047
    int jw = idx & 1023;           // word within row; j0 = 2*jw
    int u = i >> 1;
    float ex = exp2f(-(float)u * (13.287712379549449f / 512.0f));
    float a0 = (float)(2 * jw) * ex;
    float a1 = (float)(2 * jw + 1) * ex;
    float v0, v1;
    if (i & 1) { v0 = cosf(a0); v1 = cosf(a1); }
    else       { v0 = sinf(a0); v1 = sinf(a1); }
    APtw[(size_t)i * (N_ / 2) + jw] = (unsigned)f2bf(v0) | ((unsigned)f2bf(v1) << 16);
}

// ---------------------------------------------------------------------------
// Kernel 2: fp32 -> bf16 hi/lo pre-split of X, Wq|Wk (cat), Wv (hi), Wout (hi).
// ---------------------------------------------------------------------------
__global__ void split_kernel(const float* __restrict__ x,
                             const float* __restrict__ Wq, const float* __restrict__ Wk,
                             const float* __restrict__ Wv, const float* __restrict__ Wo,
                             u16* __restrict__ Xhi, u16* __restrict__ Xlo,
                             u16* __restrict__ Whi, u16* __restrict__ Wlo,
                             u16* __restrict__ Wvhi, u16* __restrict__ Wohi) {
    int i = blockIdx.x * 256 + threadIdx.x;            // 3,145,728 float4s
    const float* src; u16 *dhi, *dlo; size_t off;
    if (i < 2097152)      { src = x  + 4*(size_t)i;             dhi = Xhi;  dlo = Xlo;  off = 4*(size_t)i; }
    else if (i < 2359296) { size_t j = i - 2097152; src = Wq + 4*j; dhi = Whi; dlo = Wlo; off = 4*j; }
    else if (i < 2621440) { size_t j = i - 2359296; src = Wk + 4*j; dhi = Whi; dlo = Wlo; off = 1048576 + 4*j; }
    else if (i < 2883584) { size_t j = i - 2621440; src = Wv + 4*j; dhi = Wvhi; dlo = nullptr; off = 4*j; }
    else                  { size_t j = i - 2883584; src = Wo + 4*j; dhi = Wohi; dlo = nullptr; off = 4*j; }
    float4 v = *(const float4*)src;
    short4_t hi, lo;
    split4(v.x, v.y, v.z, v.w, &hi, &lo);
    *(short4_t*)(dhi + off) = hi;
    if (dlo) *(short4_t*)(dlo + off) = lo;
}

// ---------------------------------------------------------------------------
// Kernel 3: Q,K projections.  3-term bf16 split, m97 structure (unchanged).
// ---------------------------------------------------------------------------
__global__ __launch_bounds__(256, 4) void qk_gemm(
    const u16* __restrict__ Xhi, const u16* __restrict__ Xlo,
    const u16* __restrict__ Whi, const u16* __restrict__ Wlo,
    u16* __restrict__ Qhi, u16* __restrict__ Qlo,
    u16* __restrict__ Khi, u16* __restrict__ Klo)
{
    const int mt = blockIdx.x;   // 64
    const int nt = blockIdx.y;   // 16
    const int tid = threadIdx.x, wave = tid >> 6, lane = tid & 63;
    const int quad = lane >> 4, l16 = lane & 15;

    __shared__ __align__(16) u16 sA[2][128 * 32];
    __shared__ __align__(16) u16 sB[2][128 * 32];

    const int srow = lane >> 2;
    const int scol = (lane & 3) * 8;
    const size_t aoff = ((size_t)(mt * 128) + srow) * 1024 + scol;
    const size_t boff = ((size_t)(nt * 128) + srow) * 1024 + scol;
    const int r0 = wave * 16, r1 = 64 + wave * 16;

    float4_t acc[2][8];
#pragma unroll
    for (int i = 0; i < 2; ++i)
#pragma unroll
        for (int j = 0; j < 8; ++j) acc[i][j] = (float4_t)(0.f);

    for (int kt = 0; kt < 32; ++kt) {
        __syncthreads();
        const int kc0 = kt * 32;
        gl_lds16(Xhi + aoff + (size_t)r0 * 1024 + kc0, &sA[0][r0 * 32]);
        gl_lds16(Xhi + aoff + (size_t)r1 * 1024 + kc0, &sA[0][r1 * 32]);
        gl_lds16(Xlo + aoff + (size_t)r0 * 1024 + kc0, &sA[1][r0 * 32]);
        gl_lds16(Xlo + aoff + (size_t)r1 * 1024 + kc0, &sA[1][r1 * 32]);
        gl_lds16(Whi + boff + (size_t)r0 * 1024 + kc0, &sB[0][r0 * 32]);
        gl_lds16(Whi + boff + (size_t)r1 * 1024 + kc0, &sB[0][r1 * 32]);
        gl_lds16(Wlo + boff + (size_t)r0 * 1024 + kc0, &sB[1][r0 * 32]);
        gl_lds16(Wlo + boff + (size_t)r1 * 1024 + kc0, &sB[1][r1 * 32]);
        __syncthreads();

#pragma unroll
        for (int t = 0; t < 3; ++t) {
            const u16* As = sA[t == 2 ? 1 : 0];
            const u16* Bs = sB[t == 1 ? 1 : 0];
            short8 afr[2];
#pragma unroll
            for (int mi = 0; mi < 2; ++mi)
                afr[mi] = *(const short8*)(As + (wave * 32 + mi * 16 + l16) * 32 + quad * 8);
#pragma unroll
            for (int ne = 0; ne < 8; ++ne) {
                short8 bfr = *(const short8*)(Bs + (ne * 16 + l16) * 32 + quad * 8);
#pragma unroll
                for (int mi = 0; mi < 2; ++mi)
                    acc[mi][ne] = __builtin_amdgcn_mfma_f32_16x16x32_bf16(afr[mi], bfr, acc[mi][ne], 0, 0, 0);
            }
        }
    }

    const int b = mt >> 4, q0 = (mt & 15) * 128;
    const bool isQ = (nt < 8);
    u16* Hi = isQ ? Qhi : Khi;
    u16* Lo = isQ ? Qlo : Klo;
    const int h = isQ ? nt : nt - 8;
    const size_t base = (size_t)(b * 8 + h) * N_ * DH_;
#pragma unroll
    for (int mi = 0; mi < 2; ++mi)
#pragma unroll
        for (int ne = 0; ne < 8; ++ne)
#pragma unroll
            for (int r = 0; r < 4; ++r) {
                int q = q0 + wave * 32 + mi * 16 + quad * 4 + r;
                int e = ne * 16 + l16;
                float v = acc[mi][ne][r];
                u16 hv = f2bf(v);
                Hi[base + (size_t)q * DH_ + e] = hv;
                Lo[base + (size_t)q * DH_ + e] = f2bf(v - bf2f(hv));
            }
}

// ---------------------------------------------------------------------------
// Kernel 4: V^T[bh][e][q]  (1-term bf16, unchanged).
// ---------------------------------------------------------------------------
__global__ __launch_bounds__(256, 4) void v_gemm(
    const u16* __restrict__ Wvhi, const u16* __restrict__ Xhi,
    u16* __restrict__ VT)
{
    const int qt = blockIdx.x;   // 16
    const int bh = blockIdx.y;   // 32
    const int b = bh >> 3, h = bh & 7;
    const int tid = threadIdx.x, wave = tid >> 6, lane = tid & 63;
    const int quad = lane >> 4, l16 = lane & 15;

    __shared__ __align__(16) u16 sA[128 * 32];
    __shared__ __align__(16) u16 sB[128 * 32];

    const int srow = lane >> 2, scol = (lane & 3) * 8;
    const size_t aoff = ((size_t)(h * 128) + srow) * 1024 + scol;
    const size_t boff = ((size_t)(b * N_ + qt * 128) + srow) * 1024 + scol;
    const int r0 = wave * 16, r1 = 64 + wave * 16;

    float4_t acc[2][8];
#pragma unroll
    for (int i = 0; i < 2; ++i)
#pragma unroll
        for (int j = 0; j < 8; ++j) acc[i][j] = (float4_t)(0.f);

    for (int kt = 0; kt < 32; ++kt) {
        __syncthreads();
        const int kc0 = kt * 32;
        gl_lds16(Wvhi + aoff + (size_t)r0 * 1024 + kc0, &sA[r0 * 32]);
        gl_lds16(Wvhi + aoff + (size_t)r1 * 1024 + kc0, &sA[r1 * 32]);
        gl_lds16(Xhi  + boff + (size_t)r0 * 1024 + kc0, &sB[r0 * 32]);
        gl_lds16(Xhi  + boff + (size_t)r1 * 1024 + kc0, &sB[r1 * 32]);
        __syncthreads();

        short8 afr[2];
#pragma unroll
        for (int mi = 0; mi < 2; ++mi)
            afr[mi] = *(const short8*)(sA + (wave * 32 + mi * 16 + l16) * 32 + quad * 8);
#pragma unroll
        for (int ne = 0; ne < 8; ++ne) {
            short8 bfr = *(const short8*)(sB + (ne * 16 + l16) * 32 + quad * 8);
#pragma unroll
            for (int mi = 0; mi < 2; ++mi)
                acc[mi][ne] = __builtin_amdgcn_mfma_f32_16x16x32_bf16(afr[mi], bfr, acc[mi][ne], 0, 0, 0);
        }
    }

    u16* Cg = VT + (size_t)bh * DH_ * N_;
#pragma unroll
    for (int mi = 0; mi < 2; ++mi)
#pragma unroll
        for (int ne = 0; ne < 8; ++ne)
#pragma unroll
            for (int r = 0; r < 4; ++r) {
                int e = wave * 32 + mi * 16 + quad * 4 + r;
                int q = qt * 128 + ne * 16 + l16;
                Cg[(size_t)e * N_ + q] = f2bf(acc[mi][ne][r]);
            }
}

// ---------------------------------------------------------------------------
// Kernel 5 (pass A): l_j = sum_k exp(E[j,k]).  512 thr / 8 waves (unchanged
// from R4: chain-split kc01/kc23 + setprio; bitwise-matches attn MFMA1).
// ---------------------------------------------------------------------------
__global__ __launch_bounds__(512, 4) void rowstats_kernel(
    const u16* __restrict__ Qhi, const u16* __restrict__ Qlo,
    const u16* __restrict__ Khi, const u16* __restrict__ Klo,
    const u16* __restrict__ APt,
    const int* __restrict__ mask,
    float* __restrict__ lrow)
{
    const int jt = blockIdx.x;    // 32 j-tiles of 64
    const int bh = blockIdx.y;    // 32
    const int b = bh >> 3;
    const int tid = threadIdx.x, wave = tid >> 6, lane = tid & 63;
    const int quad = lane >> 4, l16 = lane & 15;
    const int jsub = (wave & 3) * 16, khalf = wave >> 2;

    __shared__ __align__(16) u16 ldsK[2][64 * 264];    // streamed, split (66 KB)
    __shared__ int   s_mk[2][64];
    __shared__ float psum[64 * 2];

    // Q fragments resident in registers (8 x short8 = 32 VGPR)
    short8 rQh[4], rQl[4];
    {
        const size_t qrow = ((size_t)bh * N_ + (size_t)(jt * 64 + jsub + l16)) * DH_;
#pragma unroll
        for (int kc = 0; kc < 4; ++kc) {
            rQh[kc] = *(const short8*)(Qhi + qrow + kc * 32 + quad * 8);
            rQl[kc] = *(const short8*)(Qlo + qrow + kc * 32 + quad * 8);
        }
    }

    // per-lane AP base: row = key index (khalf*32 + nk*16 + l16), col fixed
    const u16* ap_base = APt + (size_t)(khalf * 32 + l16) * N_ + jt * 64 + jsub + quad * 4;
    short4_t apc[2];
#pragma unroll
    for (int nk = 0; nk < 2; ++nk)
        apc[nk] = *(const short4_t*)(ap_base + (size_t)(nk * 16) * N_);

    // buf0: K tile 0 + mask
    {
        const size_t Kb = ((size_t)bh * N_) * DH_;
        for (int c = tid; c < 2048; c += 512) {
            int row = c >> 5, half = (c >> 4) & 1, seg = c & 15;
            *(short8*)(ldsK[0] + row * 264 + half * 128 + seg * 8) =
                *(const short8*)((half ? Klo : Khi) + Kb + (size_t)row * DH_ + seg * 8);
        }
        if (tid < 64) s_mk[0][tid] = mask[b * N_ + tid];
    }

    float p[4] = {0.f, 0.f, 0.f, 0.f};
    int mj_on[4];
#pragma unroll
    for (int r = 0; r < 4; ++r)
        mj_on[r] = mask[b * N_ + jt * 64 + jsub + quad * 4 + r];

    __syncthreads();

    for (int kt = 0; kt < 32; ++kt) {
        const int cur = kt & 1, nxt = cur ^ 1;
        short8 rK[4];
        short4_t apn[2];
        int rmk = 0;
        if (kt < 31) {
            const size_t Kb2 = ((size_t)bh * N_ + (size_t)(kt + 1) * 64) * DH_;
#pragma unroll
            for (int i = 0; i < 4; ++i) {
                int c = tid + i * 512;
                int row = c >> 5, half = (c >> 4) & 1, seg = c & 15;
                rK[i] = *(const short8*)((half ? Klo : Khi) + Kb2 + (size_t)row * DH_ + seg * 8);
            }
#pragma unroll
            for (int nk = 0; nk < 2; ++nk)
                apn[nk] = *(const short4_t*)(ap_base + (size_t)((kt + 1) * 64 + nk * 16) * N_);
            if (tid < 64) rmk = mask[b * N_ + (kt + 1) * 64 + tid];
        }

        // MFMA: S[16 j][32 k per wave], kc-major, chain split kc01/kc23
        float4_t accA[2][2];   // [half][nk]
#pragma unroll
        for (int hf = 0; hf < 2; ++hf) {
            accA[hf][0] = (float4_t)(0.f); accA[hf][1] = (float4_t)(0.f);
        }
        __builtin_amdgcn_s_setprio(1);
#pragma unroll
        for (int kc = 0; kc < 4; ++kc) {
            const int hf = kc >> 1;
            short8 bH[2], bL[2];
#pragma unroll
            for (int nk = 0; nk < 2; ++nk)
                bH[nk] = *(const short8*)(ldsK[cur] + (khalf * 32 + nk * 16 + l16) * 264 + kc * 32 + quad * 8);
#pragma unroll
            for (int nk = 0; nk < 2; ++nk)
                accA[hf][nk] = __builtin_amdgcn_mfma_f32_16x16x32_bf16(rQh[kc], bH[nk], accA[hf][nk], 0, 0, 0);
#pragma unroll
            for (int nk = 0; nk < 2; ++nk)
                accA[hf][nk] = __builtin_amdgcn_mfma_f32_16x16x32_bf16(rQl[kc], bH[nk], accA[hf][nk], 0, 0, 0);
#pragma unroll
            for (int nk = 0; nk < 2; ++nk)
                bL[nk] = *(const short8*)(ldsK[cur] + (khalf * 32 + nk * 16 + l16) * 264 + 128 + kc * 32 + quad * 8);
#pragma unroll
            for (int nk = 0; nk < 2; ++nk)
                accA[hf][nk] = __builtin_amdgcn_mfma_f32_16x16x32_bf16(rQh[kc], bL[nk], accA[hf][nk], 0, 0, 0);
        }
        __builtin_amdgcn_s_setprio(0);
        float4_t acc[2];
        acc[0] = accA[0][0] + accA[1][0];
        acc[1] = accA[0][1] + accA[1][1];

#pragma unroll
        for (int nk = 0; nk < 2; ++nk) {
            int kk = khalf * 32 + nk * 16 + l16;
            int mk = s_mk[cur][kk];
#pragma unroll
            for (int r = 0; r < 4; ++r) {
                float e = acc[nk][r] + bf2f((u16)apc[nk][r]);
                e = (mj_on[r] && mk) ? e : -1.0e9f;
                p[r] += __expf(e);
            }
        }

        if (kt < 31) {
#pragma unroll
            for (int i = 0; i < 4; ++i) {
                int c = tid + i * 512;
                int row = c >> 5, half = (c >> 4) & 1, seg = c & 15;
                *(short8*)(ldsK[nxt] + row * 264 + half * 128 + seg * 8) = rK[i];
            }
            if (tid < 64) s_mk[nxt][tid] = rmk;
            apc[0] = apn[0]; apc[1] = apn[1];
        }
        __syncthreads();
    }

    // reduce over l16 lanes, then over the two k-half waves
#pragma unroll
    for (int r = 0; r < 4; ++r) {
        float s = p[r];
        for (int off = 1; off < 16; off <<= 1)
            s += __shfl_xor(s, off, 64);
        if (l16 == 0)
            psum[(jsub + quad * 4 + r) * 2 + khalf] = s;
    }
    __syncthreads();
    if (tid < 64)
        lrow[(size_t)bh * N_ + jt * 64 + tid] = psum[tid * 2] + psum[tid * 2 + 1];
}

// ---------------------------------------------------------------------------
// Kernel 6 (pass B): y[i,e] = sum_j A[j,i] V[j,e], A = exp(E)/l_j.
// 512 thr / 8 waves, JBLK=64.  R5 design with the V-DMA destination bug
// fixed (slot offset was scaled by 8 -> OOB; now ldsV + slot*8192 + c*8).
//  - PIPELINED MFMA2: ldsA double-buffered; iter jt runs MFMA2 on tile jt-1
//    -> ONE barrier/iter.  Tail MFMA2 after the loop.  V triple-buffered.
//  - Q staged via global_load_lds with XOR swizzle (linear dest, inverse-
//    swizzled per-lane SOURCE, same-XOR read: unit ^= row&7).
// ---------------------------------------------------------------------------
__global__ __launch_bounds__(512, 2) void attn_kernel(
    const u16* __restrict__ Qhi, const u16* __restrict__ Qlo,
    const u16* __restrict__ Khi, const u16* __restrict__ Klo,
    const u16* __restrict__ VT,
    const u16* __restrict__ APt,
    const int* __restrict__ mask,
    const float* __restrict__ lrow,
    u16* __restrict__ yout,               // [BS,N,D] bf16 (ws)
    float* __restrict__ aout)             // [BS,N,N] fp32 (d_out tail)
{
    const int it = blockIdx.x;   // 16 i-tiles (keys)
    const int bh = blockIdx.y;   // 32
    const int b = bh >> 3, h = bh & 7;
    const int tid = threadIdx.x, wave = tid >> 6, lane = tid & 63;  // 8 waves
    const int quad = lane >> 4, l16 = lane & 15;

    __shared__ __align__(16) u16 ldsQ[2 * 64 * 256];   // Q_j split+swz, dbuf (64 KB, DMA)
    __shared__ __align__(16) u16 ldsV[3 * 128 * 64];   // V^T [e][j] swz, 3buf (48 KB, DMA)
    __shared__ __align__(16) u16 ldsA[2 * 128 * 72];   // A^T [i][j], dbuf    (36.9 KB)
    __shared__ __align__(16) float s_g[2][64];         // per-j: dead?-1:1/l

    // wave mapping: iq = i-quarter (MFMA1 K-rows, MFMA2 i-pod), jh = j-half /
    // e-half
    const int iq = wave >> 1, jh = wave & 1;
    const int igv0 = it * 128 + iq * 32 + l16;         // ih = 0
    const int igv1 = igv0 + 16;                        // ih = 1
    const size_t vbase = (size_t)bh * DH_ * N_;
    const size_t qbb = (size_t)bh * N_;
    const int qsw = l16 & 7;

    // K fragments resident in registers: 32 i rows/wave (16 x short8 = 64 VGPR)
    short8 rKh[4][2], rKl[4][2];
    {
        const size_t kr0 = ((size_t)bh * N_ + igv0) * DH_;
        const size_t kr1 = ((size_t)bh * N_ + igv1) * DH_;
#pragma unroll
        for (int kc = 0; kc < 4; ++kc) {
            rKh[kc][0] = *(const short8*)(Khi + kr0 + kc * 32 + quad * 8);
            rKh[kc][1] = *(const short8*)(Khi + kr1 + kc * 32 + quad * 8);
            rKl[kc][0] = *(const short8*)(Klo + kr0 + kc * 32 + quad * 8);
            rKl[kc][1] = *(const short8*)(Klo + kr1 + kc * 32 + quad * 8);
        }
    }

    // per-lane AP base: row = i (fixed per ih), col walks with jt
    const u16* apb0 = APt + (size_t)igv0 * N_ + jh * 32 + quad * 4;
    const u16* apb1 = APt + (size_t)igv1 * N_ + jh * 32 + quad * 4;
    short4_t apc[2][2];   // [ih][mj]
#pragma unroll
    for (int mj = 0; mj < 2; ++mj) {
        apc[0][mj] = *(const short4_t*)(apb0 + mj * 16);
        apc[1][mj] = *(const short4_t*)(apb1 + mj * 16);
    }

    const int ion0 = mask[b * N_ + igv0];
    const int ion1 = mask[b * N_ + igv1];

    // DMA lane decode (Q): chunk-local row / unit
    const int q_rl_off = lane >> 5;          // +row within 2-row chunk
    const int q_u = lane & 31;               // 16B unit within 512B row

    // buf0 (jt = 0): Q tile0 -> ldsQ[0], V tile0 -> slot 0
    {
#pragma unroll
        for (int i = 0; i < 4; ++i) {
            int ch = wave * 4 + i;                       // 32 chunks of 1 KB
            int rl = 2 * ch + q_rl_off;                  // local row 0..63
            int u0 = q_u ^ (rl & 7);
            const u16* src = ((u0 >> 4) ? Qlo : Qhi) + (qbb + rl) * DH_ + (u0 & 15) * 8;
            gl_lds16(src, ldsQ + ch * 512);
        }
#pragma unroll
        for (int i = 0; i < 2; ++i) {
            int c = i * 512 + wave * 64 + lane;
            int e = c >> 3, g = c & 7;
            gl_lds16(VT + vbase + (size_t)e * N_ + ((g ^ (e & 7)) * 8),
                     ldsV + (size_t)(i * 512 + wave * 64) * 8);
        }
        if (tid < 64) {
            float l = lrow[(size_t)bh * N_ + tid];
            int mj = mask[b * N_ + tid];
            s_g[0][tid] = (mj && l > 0.f) ? 1.0f / l : -1.0f;
        }
    }

    float4_t accy[2][4];   // [ni][ne]: i = iq*32+ni*16.., e = jh*64+ne*16..
#pragma unroll
    for (int ni = 0; ni < 2; ++ni)
#pragma unroll
        for (int ne = 0; ne < 4; ++ne) accy[ni][ne] = (float4_t)(0.f);

    const bool do_aout = (h == 7);
    const float inv_n = 1.0f / (float)N_;

    __syncthreads();

    for (int jt = 0; jt < 32; ++jt) {
        const int cur = jt & 1, nxt = cur ^ 1;
        const int j0 = jt * 64;

        // ---- prefetch next j-tile: Q/V via swizzled DMA, g to regs ----
        short4_t apn[2][2];
        float r_g = 0.f;
        if (jt < 31) {
            const int j0n = j0 + 64;
            const int s_wr = (jt + 1) % 3;
#pragma unroll
            for (int i = 0; i < 2; ++i) {
                int c = i * 512 + wave * 64 + lane;
                int e = c >> 3, g = c & 7;
                gl_lds16(VT + vbase + (size_t)e * N_ + j0n + ((g ^ (e & 7)) * 8),
                         ldsV + (size_t)s_wr * 8192 + (size_t)(i * 512 + wave * 64) * 8);
            }
#pragma unroll
            for (int i = 0; i < 4; ++i) {
                int ch = wave * 4 + i;
                int rl = 2 * ch + q_rl_off;
                int u0 = q_u ^ (rl & 7);
                const u16* src = ((u0 >> 4) ? Qlo : Qhi) + (qbb + j0n + rl) * DH_ + (u0 & 15) * 8;
                gl_lds16(src, ldsQ + nxt * 16384 + ch * 512);
            }
#pragma unroll
            for (int mj = 0; mj < 2; ++mj) {
                apn[0][mj] = *(const short4_t*)(apb0 + j0n + mj * 16);
                apn[1][mj] = *(const short4_t*)(apb1 + j0n + mj * 16);
            }
            if (tid < 64) {
                float l = lrow[(size_t)bh * N_ + j0n + tid];
                int mj = mask[b * N_ + j0n + tid];
                r_g = (mj && l > 0.f) ? 1.0f / l : -1.0f;
            }
        }

        // ---- MFMA1: S[j 32 (wave's half)][i 32], kc-major, chain split ----
        // per-acc order (Qhi*Khi, Qlo*Khi, Qhi*Klo) bitwise-matches rowstats
        float4_t accsA[2][2][2];   // [half][mj][ih]
#pragma unroll
        for (int hf = 0; hf < 2; ++hf)
#pragma unroll
            for (int mj = 0; mj < 2; ++mj)
#pragma unroll
                for (int ih = 0; ih < 2; ++ih) accsA[hf][mj][ih] = (float4_t)(0.f);

        const u16* qbuf = ldsQ + cur * 16384;
        __builtin_amdgcn_s_setprio(1);
#pragma unroll
        for (int kc = 0; kc < 4; ++kc) {
            const int hf = kc >> 1;
            short8 aH[2], aL[2];
#pragma unroll
            for (int mj = 0; mj < 2; ++mj)
                aH[mj] = *(const short8*)(qbuf + (jh * 32 + mj * 16 + l16) * 256 +
                                          ((kc * 4 + quad) ^ qsw) * 8);
#pragma unroll
            for (int mj = 0; mj < 2; ++mj)
#pragma unroll
                for (int ih = 0; ih < 2; ++ih)
                    accsA[hf][mj][ih] = __builtin_amdgcn_mfma_f32_16x16x32_bf16(aH[mj], rKh[kc][ih], accsA[hf][mj][ih], 0, 0, 0);
#pragma unroll
            for (int mj = 0; mj < 2; ++mj)
                aL[mj] = *(const short8*)(qbuf + (jh * 32 + mj * 16 + l16) * 256 +
                                          (((16 + kc * 4 + quad)) ^ qsw) * 8);
#pragma unroll
            for (int mj = 0; mj < 2; ++mj)
#pragma unroll
                for (int ih = 0; ih < 2; ++ih)
                    accsA[hf][mj][ih] = __builtin_amdgcn_mfma_f32_16x16x32_bf16(aL[mj], rKh[kc][ih], accsA[hf][mj][ih], 0, 0, 0);
#pragma unroll
            for (int mj = 0; mj < 2; ++mj)
#pragma unroll
                for (int ih = 0; ih < 2; ++ih)
                    accsA[hf][mj][ih] = __builtin_amdgcn_mfma_f32_16x16x32_bf16(aH[mj], rKl[kc][ih], accsA[hf][mj][ih], 0, 0, 0);
        }
        __builtin_amdgcn_s_setprio(0);

        // ---- MFMA2 on PREVIOUS tile (jt-1): ldsA[nxt], V slot (jt-1)%3 ----
        if (jt > 0) {
            const u16* aBuf = ldsA + nxt * 9216;
            const u16* vBuf = ldsV + ((jt + 2) % 3) * 8192;
            short8 afrA[2][2];
#pragma unroll
            for (int ni = 0; ni < 2; ++ni)
#pragma unroll
                for (int ks = 0; ks < 2; ++ks)
                    afrA[ni][ks] = *(const short8*)(aBuf + (iq * 32 + ni * 16 + l16) * 72 + ks * 32 + quad * 8);
            __builtin_amdgcn_s_setprio(1);
#pragma unroll
            for (int ne = 0; ne < 4; ++ne) {
#pragma unroll
                for (int ks = 0; ks < 2; ++ks) {
                    short8 bfr = *(const short8*)(vBuf + (size_t)(jh * 64 + ne * 16 + l16) * 64 +
                                                  (((ks * 4 + quad) ^ (l16 & 7)) * 8));
#pragma unroll
                    for (int ni = 0; ni < 2; ++ni)
                        accy[ni][ne] = __builtin_amdgcn_mfma_f32_16x16x32_bf16(afrA[ni][ks], bfr, accy[ni][ne], 0, 0, 0);
                }
            }
            __builtin_amdgcn_s_setprio(0);
        }

        // ---- epilogue: A = exp(E)*g -> ldsA[cur]; h==7: fp32 aout ----
        {
            u16* aBufW = ldsA + cur * 9216;
#pragma unroll
            for (int mj = 0; mj < 2; ++mj) {
                float4_t g4 = *(const float4_t*)(&s_g[cur][jh * 32 + mj * 16 + quad * 4]);
#pragma unroll
                for (int ih = 0; ih < 2; ++ih) {
                    float4_t accs = accsA[0][mj][ih] + accsA[1][mj][ih];
                    const int ig = ih ? igv1 : igv0;
                    const int ion = ih ? ion1 : ion0;
                    short4_t pk;
#pragma unroll
                    for (int r = 0; r < 4; ++r) {
                        int jl = jh * 32 + mj * 16 + quad * 4 + r;
                        float e = accs[r] + bf2f((u16)apc[ih][mj][r]);
                        float g = g4[r];
                        float a = (g < 0.f) ? inv_n : (ion ? __expf(e) * g : 0.f);
                        pk[r] = (short)f2bf(a);
                        if (do_aout)
                            aout[((size_t)(b * N_ + j0 + jl)) * N_ + ig] = a;
                    }
                    *(short4_t*)(aBufW + (size_t)(iq * 32 + ih * 16 + l16) * 72 + jh * 32 + mj * 16 + quad * 4) = pk;
                }
            }
        }

        if (jt < 31) {
            if (tid < 64) s_g[nxt][tid] = r_g;
#pragma unroll
            for (int mj = 0; mj < 2; ++mj) {
                apc[0][mj] = apn[0][mj];
                apc[1][mj] = apn[1][mj];
            }
        }
        __syncthreads();   // ONE barrier: DMA drained, ldsA[cur] visible,
                           // ldsQ[cur]/V[(jt-1)%3] reads done
    }

    // ---- tail MFMA2: tile 31 (ldsA[1], V slot 31%3 = 1) ----
    {
        const u16* aBuf = ldsA + 1 * 9216;
        const u16* vBuf = ldsV + 1 * 8192;
        short8 afrA[2][2];
#pragma unroll
        for (int ni = 0; ni < 2; ++ni)
#pragma unroll
            for (int ks = 0; ks < 2; ++ks)
                afrA[ni][ks] = *(const short8*)(aBuf + (iq * 32 + ni * 16 + l16) * 72 + ks * 32 + quad * 8);
#pragma unroll
        for (int ne = 0; ne < 4; ++ne) {
#pragma unroll
            for (int ks = 0; ks < 2; ++ks) {
                short8 bfr = *(const short8*)(vBuf + (size_t)(jh * 64 + ne * 16 + l16) * 64 +
                                              (((ks * 4 + quad) ^ (l16 & 7)) * 8));
#pragma unroll
                for (int ni = 0; ni < 2; ++ni)
                    accy[ni][ne] = __builtin_amdgcn_mfma_f32_16x16x32_bf16(afrA[ni][ks], bfr, accy[ni][ne], 0, 0, 0);
            }
        }
    }

#pragma unroll
    for (int ni = 0; ni < 2; ++ni)
#pragma unroll
        for (int ne = 0; ne < 4; ++ne)
#pragma unroll
            for (int r = 0; r < 4; ++r) {
                int irow = iq * 32 + ni * 16 + quad * 4 + r;
                int e = jh * 64 + ne * 16 + l16;
                yout[((size_t)b * N_ + it * 128 + irow) * D_ + h * DH_ + e] =
                    f2bf(accy[ni][ne][r]);
            }
}

// ---------------------------------------------------------------------------
// Kernel 7: out[m,o] = sum_d y[m,d] Wout[o,d]  (unchanged).
// ---------------------------------------------------------------------------
__global__ __launch_bounds__(256, 4) void outgemm_kernel(
    const u16* __restrict__ A,     // y   [8192][1024] bf16
    const u16* __restrict__ B,     // Wout[1024][1024] bf16 (hi)
    float* __restrict__ C)         // out [8192][1024] fp32
{
    const int nt = blockIdx.x;   // 8
    const int mt = blockIdx.y;   // 64
    const int tid = threadIdx.x, wave = tid >> 6, lane = tid & 63;
    const int quad = lane >> 4, l16 = lane & 15;

    __shared__ __align__(16) u16 sA[128 * 32];
    __shared__ __align__(16) u16 sB[128 * 32];

    const int srow = lane >> 2, scol = (lane & 3) * 8;
    const size_t aoff = ((size_t)(mt * 128) + srow) * 1024 + scol;
    const size_t boff = ((size_t)(nt * 128) + srow) * 1024 + scol;
    const int r0 = wave * 16, r1 = 64 + wave * 16;

    float4_t acc[2][8];
#pragma unroll
    for (int i = 0; i < 2; ++i)
#pragma unroll
        for (int j = 0; j < 8; ++j) acc[i][j] = (float4_t)(0.f);

    for (int kt = 0; kt < 32; ++kt) {
        __syncthreads();
        const int kc0 = kt * 32;
        gl_lds16(A + aoff + (size_t)r0 * 1024 + kc0, &sA[r0 * 32]);
        gl_lds16(A + aoff + (size_t)r1 * 1024 + kc0, &sA[r1 * 32]);
        gl_lds16(B + boff + (size_t)r0 * 1024 + kc0, &sB[r0 * 32]);
        gl_lds16(B + boff + (size_t)r1 * 1024 + kc0, &sB[r1 * 32]);
        __syncthreads();

        short8 afr[2];
#pragma unroll
        for (int mi = 0; mi < 2; ++mi)
            afr[mi] = *(const short8*)(sA + (wave * 32 + mi * 16 + l16) * 32 + quad * 8);
#pragma unroll
        for (int ne = 0; ne < 8; ++ne) {
            short8 bfr = *(const short8*)(sB + (ne * 16 + l16) * 32 + quad * 8);
#pragma unroll
            for (int mi = 0; mi < 2; ++mi)
                acc[mi][ne] = __builtin_amdgcn_mfma_f32_16x16x32_bf16(afr[mi], bfr, acc[mi][ne], 0, 0, 0);
        }
    }

#pragma unroll
    for (int mi = 0; mi < 2; ++mi)
#pragma unroll
        for (int ne = 0; ne < 8; ++ne)
#pragma unroll
            for (int r = 0; r < 4; ++r) {
                int row = mt * 128 + wave * 32 + mi * 16 + quad * 4 + r;
                int col = nt * 128 + ne * 16 + l16;
                C[(size_t)row * D_ + col] = acc[mi][ne][r];
            }
}

// ---------------------------------------------------------------------------
extern "C" void kernel_launch(void* const* d_in, const int* in_sizes, int n_in,
                              void* d_out, int out_size, void* d_ws, size_t ws_size,
                              hipStream_t stream)
{
    const float* x   = (const float*)d_in[0];
    const int*   msk = (const int*)d_in[1];
    const float* Wq  = (const float*)d_in[2];
    const float* Wk  = (const float*)d_in[3];
    const float* Wv  = (const float*)d_in[4];
    const float* Wo  = (const float*)d_in[5];

    float* out  = (float*)d_out;                         // [4,2048,1024] fp32
    float* aout = out + (size_t)BS_ * N_ * D_;           // [4,2048,2048] fp32

    // transient split buffers in d_out (dead before attn/outgemm overwrite)
    u16* Whi  = (u16*)d_out;                       // 2048*1024
    u16* Wlo  = Whi  + (size_t)2048 * 1024;        // 2048*1024
    u16* Wvhi = Wlo  + (size_t)2048 * 1024;        // 1024*1024
    u16* Xhi  = Wvhi + (size_t)1024 * 1024;        // 8192*1024
    u16* Xlo  = Xhi  + (size_t)8192 * 1024;        // 8192*1024

    // workspace (111.4 MB)
    char* w = (char*)d_ws;
    u16* APt = (u16*)w;                       w += (size_t)N_ * N_ * 2;   // transposed AP
    const size_t szqk = (size_t)BS_ * H_ * N_ * DH_ * 2;
    u16* Qhi = (u16*)w; w += szqk;
    u16* Qlo = (u16*)w; w += szqk;
    u16* Khi = (u16*)w; w += szqk;
    u16* Klo = (u16*)w; w += szqk;
    u16* VT  = (u16*)w; w += szqk;
    float* lrow = (float*)w;                  w += (size_t)BS_ * H_ * N_ * 4;
    u16* Wohi = (u16*)w;                      w += (size_t)D_ * D_ * 2;
    u16* yb   = (u16*)w;                      w += (size_t)BS_ * N_ * D_ * 2;

    apt_kernel<<<8192, 256, 0, stream>>>((unsigned int*)APt);
    split_kernel<<<12288, 256, 0, stream>>>(x, Wq, Wk, Wv, Wo,
                                            Xhi, Xlo, Whi, Wlo, Wvhi, Wohi);
    qk_gemm<<<dim3(64, 16), 256, 0, stream>>>(Xhi, Xlo, Whi, Wlo,
                                              Qhi, Qlo, Khi, Klo);
    v_gemm<<<dim3(16, 32), 256, 0, stream>>>(Wvhi, Xhi, VT);
    rowstats_kernel<<<dim3(32, 32), 512, 0, stream>>>(Qhi, Qlo, Khi, Klo, APt, msk, lrow);
    attn_kernel<<<dim3(16, 32), 512, 0, stream>>>(Qhi, Qlo, Khi, Klo, VT, APt, msk,
                                                  lrow, yb, aout);
    outgemm_kernel<<<dim3(8, 64), 256, 0, stream>>>(yb, Wohi, out);
}